// Round 1
// baseline (2685.514 us; speedup 1.0000x reference)
//
#include <hip/hip_runtime.h>

// ---------------------------------------------------------------------------
// LIM-DFPN forward, fp32 baseline.
// Structure: cummax-scan kernels build the 5C concat; one templated
// implicit-GEMM conv kernel (128x128 or 64x64 tile, 8x8/4x4 per-thread,
// BK=16) handles every conv; split-K + generic reduce/epilogue kernel for
// low-parallelism convs; epilogue (bias / upsampled residual adds / gated
// merge / ReLU-on-input) fused where S==1.
// ---------------------------------------------------------------------------

struct Epi {
  const float* bias;
  const float* r1; int r1sh;      // residual 1 (channels==256), nearest-upsample shift
  const float* r2; int r2sh;      // residual 2
  const float* gamma;             // 1-element gate
  const float* other;             // gate partner (same shape as output)
  int gate_mode;                  // 0 none; 1: g*other+(1-g)*v; 2: g*v+(1-g)*other
};

__device__ __forceinline__ float apply_epi(float v, const Epi& ep, int m, int b,
                                           int oh, int ow, int OH, int OW,
                                           size_t oidx)
{
  if (ep.bias) v += ep.bias[m];
  if (ep.r1) {
    int RH = OH >> ep.r1sh, RW = OW >> ep.r1sh;
    v += ep.r1[(((size_t)b * 256 + m) * RH + (oh >> ep.r1sh)) * RW + (ow >> ep.r1sh)];
  }
  if (ep.r2) {
    int RH = OH >> ep.r2sh, RW = OW >> ep.r2sh;
    v += ep.r2[(((size_t)b * 256 + m) * RH + (oh >> ep.r2sh)) * RW + (ow >> ep.r2sh)];
  }
  if (ep.gate_mode) {
    float g = *ep.gamma;
    float o = ep.other[oidx];
    v = (ep.gate_mode == 1) ? (g * o + (1.f - g) * v) : (g * v + (1.f - g) * o);
  }
  return v;
}

// ---------------------------------------------------------------------------
// Cummax scans: one block per (batch-local) channel plane. Builds the 5C
// concat: [x, prefH, sufH, prefW, sufW]. x/cat pointers are per-batch bases.
// ---------------------------------------------------------------------------
template<int S, int L2S>
__global__ __launch_bounds__(256)
void k_scan(const float* __restrict__ x, float* __restrict__ cat, int C)
{
  int c = blockIdx.x;
  __shared__ float pl[S][S + 1];
  __shared__ float rp[S][S + 1];
  __shared__ float rs[S][S + 1];
  const float* xp = x + (size_t)c * (S * S);
  float* c0 = cat + (size_t)c * (S * S);
  for (int idx = threadIdx.x; idx < S * S; idx += 256) {
    float v = xp[idx];
    pl[idx >> L2S][idx & (S - 1)] = v;
    c0[idx] = v;
  }
  __syncthreads();
  int t = threadIdx.x;
  if (t < S) {                      // column scans along H (coalesced writes)
    float* c1 = cat + ((size_t)(C + c)) * (S * S);
    float m = -INFINITY;
    for (int h = 0; h < S; ++h) { m = fmaxf(m, pl[h][t]); c1[h * S + t] = m; }
    float* c2 = cat + ((size_t)(2 * C + c)) * (S * S);
    m = -INFINITY;
    for (int h = S - 1; h >= 0; --h) { m = fmaxf(m, pl[h][t]); c2[h * S + t] = m; }
  } else if (t < 2 * S) {           // row scans along W into LDS
    int h = t - S;
    float m = -INFINITY;
    for (int w = 0; w < S; ++w) { m = fmaxf(m, pl[h][w]); rp[h][w] = m; }
    m = -INFINITY;
    for (int w = S - 1; w >= 0; --w) { m = fmaxf(m, pl[h][w]); rs[h][w] = m; }
  }
  __syncthreads();
  float* c3 = cat + ((size_t)(3 * C + c)) * (S * S);
  float* c4 = cat + ((size_t)(4 * C + c)) * (S * S);
  for (int idx = threadIdx.x; idx < S * S; idx += 256) {
    int h = idx >> L2S, w = idx & (S - 1);
    c3[idx] = rp[h][w];
    c4[idx] = rs[h][w];
  }
}

// ---------------------------------------------------------------------------
// Implicit-GEMM conv. M = Cout, N = B*OH*OW, K = Cin*KH*KW.
// Tile BM x BN, 256 threads, per-thread (BM/16)x(BN/16). BK = 16.
// Split-K via blockIdx.z (klen K-elements per split); FUSE applies the
// epilogue and writes final NCHW, else writes raw partial z at Out+z*Cout*N.
// ---------------------------------------------------------------------------
template<int KHW, int KW, int STR, int PAD, int BM, int BN, bool RELU_IN, bool FUSE>
__global__ __launch_bounds__(256)
void k_conv(const float* __restrict__ X, const float* __restrict__ Wt,
            float* __restrict__ Out, int Cin, int Cout,
            int IH, int IW, int l2ohow, int l2ow,
            int K, int klen, int N, Epi ep)
{
  constexpr int TM = BM / 16, TN = BN / 16;
  __shared__ float As[16][BM + 4];
  __shared__ float Bs[16][BN + 4];
  const int n0 = blockIdx.x * BN;
  const int m0 = blockIdx.y * BM;
  const int kb = blockIdx.z * klen;
  const int tid = threadIdx.x;
  const int tx = tid & 15, ty = tid >> 4;
  const int OW = 1 << l2ow;
  const int OHOW = 1 << l2ohow;

  float acc[TM][TN];
#pragma unroll
  for (int i = 0; i < TM; ++i)
#pragma unroll
    for (int j = 0; j < TN; ++j) acc[i][j] = 0.f;

  for (int k0 = kb; k0 < kb + klen; k0 += 16) {
    // ---- stage A (weights) BMx16, transposed into As[k][m] ----
#pragma unroll
    for (int r = 0; r < BM / 64; ++r) {
      int row = (tid >> 2) + r * 64;
      int col = (tid & 3) * 4;
      float4 w4 = *(const float4*)&Wt[(size_t)(m0 + row) * K + (k0 + col)];
      As[col + 0][row] = w4.x; As[col + 1][row] = w4.y;
      As[col + 2][row] = w4.z; As[col + 3][row] = w4.w;
    }
    // ---- stage B (im2col input) 16xBN ----
#pragma unroll
    for (int r = 0; r < (16 * BN) / 256; ++r) {
      int idx = tid + r * 256;
      int nl = idx % BN;
      int kl = idx / BN;
      int k = k0 + kl;
      int c, kh, kw;
      if (KHW == 1) { c = k; kh = 0; kw = 0; }
      else { c = k / KHW; int rr = k - c * KHW; kh = rr / KW; kw = rr - kh * KW; }
      int n = n0 + nl;
      int b = n >> l2ohow;
      int p = n & (OHOW - 1);
      int oh = p >> l2ow;
      int ow = p & (OW - 1);
      int ih = oh * STR - PAD + kh;
      int iw = ow * STR - PAD + kw;
      float v = 0.f;
      bool ok = (PAD == 0) ? true
                           : ((unsigned)ih < (unsigned)IH && (unsigned)iw < (unsigned)IW);
      if (ok) v = X[(((size_t)b * Cin + c) * IH + ih) * IW + iw];
      if (RELU_IN) v = fmaxf(v, 0.f);
      Bs[kl][nl] = v;
    }
    __syncthreads();
    // ---- compute ----
#pragma unroll
    for (int k = 0; k < 16; ++k) {
      float a[TM], bv[TN];
#pragma unroll
      for (int q = 0; q < TM / 4; ++q) {
        float4 t4 = *(const float4*)&As[k][q * 64 + ty * 4];
        a[q * 4 + 0] = t4.x; a[q * 4 + 1] = t4.y; a[q * 4 + 2] = t4.z; a[q * 4 + 3] = t4.w;
      }
#pragma unroll
      for (int q = 0; q < TN / 4; ++q) {
        float4 t4 = *(const float4*)&Bs[k][q * 64 + tx * 4];
        bv[q * 4 + 0] = t4.x; bv[q * 4 + 1] = t4.y; bv[q * 4 + 2] = t4.z; bv[q * 4 + 3] = t4.w;
      }
#pragma unroll
      for (int i = 0; i < TM; ++i)
#pragma unroll
        for (int j = 0; j < TN; ++j) acc[i][j] = fmaf(a[i], bv[j], acc[i][j]);
    }
    __syncthreads();
  }

  const size_t partbase = FUSE ? 0 : (size_t)blockIdx.z * (size_t)Cout * (size_t)N;
  const int OH = OHOW >> l2ow;
#pragma unroll
  for (int i = 0; i < TM; ++i) {
    int m = m0 + (i >> 2) * 64 + ty * 4 + (i & 3);
#pragma unroll
    for (int j = 0; j < TN; ++j) {
      int nl = (j >> 2) * 64 + tx * 4 + (j & 3);
      int n = n0 + nl;
      int b = n >> l2ohow;
      int p = n & (OHOW - 1);
      size_t oidx = ((size_t)b * Cout + m) * OHOW + p;
      float v = acc[i][j];
      if (FUSE) {
        int oh = p >> l2ow, ow = p & (OW - 1);
        Out[oidx] = apply_epi(v, ep, m, b, oh, ow, OH, OW, oidx);
      } else {
        Out[partbase + oidx] = v;
      }
    }
  }
}

// ---------------------------------------------------------------------------
// Split-K reduce + epilogue. part holds S full-tensor partials; Out is NCHW.
// ---------------------------------------------------------------------------
__global__ __launch_bounds__(256)
void k_reduce(const float* __restrict__ part, int S, size_t E,
              float* __restrict__ Out, int l2cout, int l2oh, int l2ow, Epi ep)
{
  size_t stride = (size_t)gridDim.x * 256;
  int OW = 1 << l2ow, OH = 1 << l2oh;
  for (size_t e = (size_t)blockIdx.x * 256 + threadIdx.x; e < E; e += stride) {
    float v = 0.f;
    for (int s = 0; s < S; ++s) v += part[(size_t)s * E + e];
    int ow = (int)(e & (OW - 1));
    size_t t = e >> l2ow;
    int oh = (int)(t & (OH - 1));
    t >>= l2oh;
    int m = (int)(t & ((1 << l2cout) - 1));
    int b = (int)(t >> l2cout);
    Out[e] = apply_epi(v, ep, m, b, oh, ow, OH, OW, e);
  }
}

// ---------------------------------------------------------------------------
extern "C" void kernel_launch(void* const* d_in, const int* in_sizes, int n_in,
                              void* d_out, int out_size, void* d_ws, size_t ws_size,
                              hipStream_t stream)
{
  (void)in_sizes; (void)n_in; (void)out_size;
  const float* C3    = (const float*)d_in[0];
  const float* C4    = (const float*)d_in[1];
  const float* C5    = (const float*)d_in[2];
  const float* ba3_w = (const float*)d_in[3];  const float* ba3_b = (const float*)d_in[4];
  const float* ba4_w = (const float*)d_in[5];  const float* ba4_b = (const float*)d_in[6];
  const float* ba5_w = (const float*)d_in[7];  const float* ba5_b = (const float*)d_in[8];
  const float* p5_1_w  = (const float*)d_in[9];  const float* p5_1_b  = (const float*)d_in[10];
  const float* p5_1d_w = (const float*)d_in[11]; const float* p5_1d_b = (const float*)d_in[12];
  const float* p5_2_w  = (const float*)d_in[13]; const float* p5_2_b  = (const float*)d_in[14];
  const float* p4_1_w  = (const float*)d_in[15]; const float* p4_1_b  = (const float*)d_in[16];
  const float* p4_1d_w = (const float*)d_in[17]; const float* p4_1d_b = (const float*)d_in[18];
  const float* p4_2_w  = (const float*)d_in[19]; const float* p4_2_b  = (const float*)d_in[20];
  const float* p3_1_w  = (const float*)d_in[21]; const float* p3_1_b  = (const float*)d_in[22];
  const float* p3_1d_w = (const float*)d_in[23]; const float* p3_1d_b = (const float*)d_in[24];
  const float* p3_2_w  = (const float*)d_in[25]; const float* p3_2_b  = (const float*)d_in[26];
  const float* p6_w  = (const float*)d_in[27]; const float* p6_b  = (const float*)d_in[28];
  const float* p7_w  = (const float*)d_in[29]; const float* p7_b  = (const float*)d_in[30];
  const float* c34_w = (const float*)d_in[31]; const float* c34_b = (const float*)d_in[32];
  const float* c45_w = (const float*)d_in[33]; const float* c45_b = (const float*)d_in[34];
  const float* c35_w = (const float*)d_in[35]; const float* c35_b = (const float*)d_in[36];
  const float* g3 = (const float*)d_in[37];
  const float* g4 = (const float*)d_in[38];
  const float* g5 = (const float*)d_in[39];

  float* out = (float*)d_out;
  float* O3 = out;
  float* O4 = out + 8388608;
  float* O5 = out + 10485760;
  float* P6 = out + 11010048;
  float* P7 = out + 11141120;

  float* ws = (float*)d_ws;
  const bool full = ws_size >= (size_t)226492416;  // full-batch cat path

  // intermediates (live after the BA phase; same offsets both modes)
  float* P3d   = ws + 0;
  float* P3d1  = ws + 8388608;
  float* P3d2  = ws + 10485760;
  float* P4d   = ws + 11010048;
  float* P4d1  = ws + 13107200;
  float* P5pre = ws + 13631488;
  float* P5s   = ws + 14155776;
  float* P4pre = ws + 14680064;   // ends at 16777216

  float *cat, *part_ba, *part, *C3_BA, *C4_BA, *C5_BA;
  if (full) {
    cat     = ws;                 // 41,943,040 floats
    part_ba = ws + 25165824;      // inside cat region, after intermediates
    part    = part_ba;
    C3_BA   = ws + 41943040;
    C4_BA   = ws + 50331648;
    C5_BA   = ws + 54525952;      // ends 56,623,104 floats (226.5 MB)
  } else {
    cat     = ws;                 // per-batch cat, <= 5,242,880 floats
    part_ba = ws + 5242880;
    part    = ws + 16777216;      // 8,388,608 floats
    C3_BA   = ws + 25165824;
    C4_BA   = ws + 33554432;
    C5_BA   = ws + 37748736;      // ends 39,845,888 floats (159.4 MB)
  }
  float* P3pre = C3_BA;           // C3_BA dead after P3d; reuse

  const Epi enone = {nullptr, nullptr, 0, nullptr, 0, nullptr, nullptr, 0};

  // ============================ BA phase ============================
  if (full) {
    for (int b = 0; b < 8; ++b)
      k_scan<64, 6><<<256, 256, 0, stream>>>(C3 + (size_t)b * 1048576,
                                             cat + (size_t)b * 5242880, 256);
    {
      Epi ep = {ba3_b, nullptr, 0, nullptr, 0, nullptr, nullptr, 0};
      k_conv<1,1,1,0,128,128,false,true><<<dim3(256,2,1),256,0,stream>>>(
        cat, ba3_w, C3_BA, 1280, 256, 64, 64, 12, 6, 1280, 1280, 32768, ep);
    }
    for (int b = 0; b < 8; ++b)
      k_scan<32, 5><<<512, 256, 0, stream>>>(C4 + (size_t)b * 524288,
                                             cat + (size_t)b * 2621440, 512);
    k_conv<1,1,1,0,128,128,false,false><<<dim3(64,4,2),256,0,stream>>>(
        cat, ba4_w, part_ba, 2560, 512, 32, 32, 10, 5, 2560, 1280, 8192, enone);
    {
      Epi ep = {ba4_b, nullptr, 0, nullptr, 0, nullptr, nullptr, 0};
      k_reduce<<<2048, 256, 0, stream>>>(part_ba, 2, (size_t)4194304, C4_BA, 9, 5, 5, ep);
    }
    for (int b = 0; b < 8; ++b)
      k_scan<16, 4><<<1024, 256, 0, stream>>>(C5 + (size_t)b * 262144,
                                              cat + (size_t)b * 1310720, 1024);
    k_conv<1,1,1,0,128,128,false,false><<<dim3(16,8,4),256,0,stream>>>(
        cat, ba5_w, part_ba, 5120, 1024, 16, 16, 8, 4, 5120, 1280, 2048, enone);
    {
      Epi ep = {ba5_b, nullptr, 0, nullptr, 0, nullptr, nullptr, 0};
      k_reduce<<<2048, 256, 0, stream>>>(part_ba, 4, (size_t)2097152, C5_BA, 10, 4, 4, ep);
    }
  } else {
    for (int b = 0; b < 8; ++b) {
      k_scan<64, 6><<<256, 256, 0, stream>>>(C3 + (size_t)b * 1048576, cat, 256);
      k_conv<1,1,1,0,128,128,false,false><<<dim3(32,2,8),256,0,stream>>>(
          cat, ba3_w, part_ba, 1280, 256, 64, 64, 12, 6, 1280, 160, 4096, enone);
      Epi ep = {ba3_b, nullptr, 0, nullptr, 0, nullptr, nullptr, 0};
      k_reduce<<<1024, 256, 0, stream>>>(part_ba, 8, (size_t)1048576,
                                         C3_BA + (size_t)b * 1048576, 8, 6, 6, ep);
    }
    for (int b = 0; b < 8; ++b) {
      k_scan<32, 5><<<512, 256, 0, stream>>>(C4 + (size_t)b * 524288, cat, 512);
      k_conv<1,1,1,0,128,128,false,false><<<dim3(8,4,16),256,0,stream>>>(
          cat, ba4_w, part_ba, 2560, 512, 32, 32, 10, 5, 2560, 160, 1024, enone);
      Epi ep = {ba4_b, nullptr, 0, nullptr, 0, nullptr, nullptr, 0};
      k_reduce<<<512, 256, 0, stream>>>(part_ba, 16, (size_t)524288,
                                        C4_BA + (size_t)b * 524288, 9, 5, 5, ep);
    }
    for (int b = 0; b < 8; ++b) {
      k_scan<16, 4><<<1024, 256, 0, stream>>>(C5 + (size_t)b * 262144, cat, 1024);
      k_conv<1,1,1,0,128,128,false,false><<<dim3(2,8,32),256,0,stream>>>(
          cat, ba5_w, part_ba, 5120, 1024, 16, 16, 8, 4, 5120, 160, 256, enone);
      Epi ep = {ba5_b, nullptr, 0, nullptr, 0, nullptr, nullptr, 0};
      k_reduce<<<256, 256, 0, stream>>>(part_ba, 32, (size_t)262144,
                                        C5_BA + (size_t)b * 262144, 10, 4, 4, ep);
    }
  }

  // ============================ dual (bottom-up) path ============================
  {
    Epi ep = {p3_1d_b, nullptr, 0, nullptr, 0, nullptr, nullptr, 0};
    k_conv<1,1,1,0,128,128,false,true><<<dim3(256,2,1),256,0,stream>>>(
      C3_BA, p3_1d_w, P3d, 256, 256, 64, 64, 12, 6, 256, 256, 32768, ep);
  }
  k_conv<9,3,2,1,128,128,false,false><<<dim3(64,2,4),256,0,stream>>>(
      P3d, c34_w, part, 256, 256, 64, 64, 10, 5, 2304, 576, 8192, enone);
  {
    Epi ep = {c34_b, nullptr, 0, nullptr, 0, nullptr, nullptr, 0};
    k_reduce<<<2048, 256, 0, stream>>>(part, 4, (size_t)2097152, P3d1, 8, 5, 5, ep);
  }
  k_conv<4,2,2,0,128,128,false,false><<<dim3(16,2,16),256,0,stream>>>(
      P3d1, c35_w, part, 256, 256, 32, 32, 8, 4, 1024, 64, 2048, enone);
  {
    Epi ep = {c35_b, nullptr, 0, nullptr, 0, nullptr, nullptr, 0};
    k_reduce<<<1024, 256, 0, stream>>>(part, 16, (size_t)524288, P3d2, 8, 4, 4, ep);
  }
  k_conv<1,1,1,0,128,128,false,false><<<dim3(64,2,4),256,0,stream>>>(
      C4_BA, p4_1d_w, part, 512, 256, 32, 32, 10, 5, 512, 128, 8192, enone);
  {
    Epi ep = {p4_1d_b, P3d1, 0, nullptr, 0, nullptr, nullptr, 0};
    k_reduce<<<2048, 256, 0, stream>>>(part, 4, (size_t)2097152, P4d, 8, 5, 5, ep);
  }
  k_conv<4,2,2,0,128,128,false,false><<<dim3(16,2,16),256,0,stream>>>(
      P4d, c45_w, part, 256, 256, 32, 32, 8, 4, 1024, 64, 2048, enone);
  {
    Epi ep = {c45_b, nullptr, 0, nullptr, 0, nullptr, nullptr, 0};
    k_reduce<<<1024, 256, 0, stream>>>(part, 16, (size_t)524288, P4d1, 8, 4, 4, ep);
  }

  // ============================ top-down path ============================
  k_conv<1,1,1,0,128,128,false,false><<<dim3(16,2,16),256,0,stream>>>(
      C5, p5_1_w, part, 1024, 256, 16, 16, 8, 4, 1024, 64, 2048, enone);
  {
    Epi ep = {p5_1_b, nullptr, 0, nullptr, 0, nullptr, nullptr, 0};
    k_reduce<<<1024, 256, 0, stream>>>(part, 16, (size_t)524288, P5pre, 8, 4, 4, ep);
  }
  k_conv<9,3,1,1,128,128,false,false><<<dim3(16,2,16),256,0,stream>>>(
      P5pre, p5_2_w, part, 256, 256, 16, 16, 8, 4, 2304, 144, 2048, enone);
  {
    Epi ep = {p5_2_b, nullptr, 0, nullptr, 0, nullptr, nullptr, 0};
    k_reduce<<<1024, 256, 0, stream>>>(part, 16, (size_t)524288, P5s, 8, 4, 4, ep);
  }
  k_conv<1,1,1,0,128,128,false,false><<<dim3(64,2,4),256,0,stream>>>(
      C4, p4_1_w, part, 512, 256, 32, 32, 10, 5, 512, 128, 8192, enone);
  {
    Epi ep = {p4_1_b, P5pre, 1, nullptr, 0, nullptr, nullptr, 0};
    k_reduce<<<2048, 256, 0, stream>>>(part, 4, (size_t)2097152, P4pre, 8, 5, 5, ep);
  }
  k_conv<9,3,1,1,128,128,false,false><<<dim3(64,2,4),256,0,stream>>>(
      P4pre, p4_2_w, part, 256, 256, 32, 32, 10, 5, 2304, 576, 8192, enone);
  {
    Epi ep = {p4_2_b, nullptr, 0, nullptr, 0, g4, P4d, 1};   // O4
    k_reduce<<<2048, 256, 0, stream>>>(part, 4, (size_t)2097152, O4, 8, 5, 5, ep);
  }
  {
    Epi ep = {p3_1_b, P4pre, 1, P5pre, 2, nullptr, nullptr, 0};
    k_conv<1,1,1,0,128,128,false,true><<<dim3(256,2,1),256,0,stream>>>(
      C3, p3_1_w, P3pre, 256, 256, 64, 64, 12, 6, 256, 256, 32768, ep);
  }
  {
    Epi ep = {p3_2_b, nullptr, 0, nullptr, 0, g3, P3d, 1};   // O3
    k_conv<9,3,1,1,128,128,false,true><<<dim3(256,2,1),256,0,stream>>>(
      P3pre, p3_2_w, O3, 256, 256, 64, 64, 12, 6, 2304, 2304, 32768, ep);
  }
  k_conv<1,1,1,0,128,128,false,false><<<dim3(16,2,16),256,0,stream>>>(
      C5_BA, p5_1d_w, part, 1024, 256, 16, 16, 8, 4, 1024, 64, 2048, enone);
  {
    Epi ep = {p5_1d_b, P4d1, 0, P3d2, 0, g5, P5s, 2};        // O5
    k_reduce<<<1024, 256, 0, stream>>>(part, 16, (size_t)524288, O5, 8, 4, 4, ep);
  }

  // ============================ P6 / P7 ============================
  k_conv<9,3,2,1,128,128,false,false><<<dim3(4,2,64),256,0,stream>>>(
      C5, p6_w, part, 1024, 256, 16, 16, 6, 3, 9216, 144, 512, enone);
  {
    Epi ep = {p6_b, nullptr, 0, nullptr, 0, nullptr, nullptr, 0};
    k_reduce<<<512, 256, 0, stream>>>(part, 64, (size_t)131072, P6, 8, 3, 3, ep);
  }
  k_conv<9,3,2,1,64,64,true,false><<<dim3(2,4,48),256,0,stream>>>(
      P6, p7_w, part, 256, 256, 8, 8, 4, 2, 2304, 48, 128, enone);
  {
    Epi ep = {p7_b, nullptr, 0, nullptr, 0, nullptr, nullptr, 0};
    k_reduce<<<128, 256, 0, stream>>>(part, 48, (size_t)32768, P7, 8, 2, 2, ep);
  }
}

// Round 3
// 1301.094 us; speedup vs baseline: 2.0640x; 2.0640x over previous
//
#include <hip/hip_runtime.h>

typedef unsigned short u16;
typedef __attribute__((ext_vector_type(8))) short s8v;
typedef __attribute__((ext_vector_type(4))) float f4v;

__device__ __forceinline__ u16 f2bf(float f) {
  unsigned int x = __float_as_uint(f);
  return (u16)((x + 0x7fffu + ((x >> 16) & 1u)) >> 16);
}
__device__ __forceinline__ float bf2f(u16 u) {
  return __uint_as_float(((unsigned int)u) << 16);
}
__device__ __forceinline__ void gload16(const void* g, void* l) {
  __builtin_amdgcn_global_load_lds(
      (const __attribute__((address_space(1))) void*)g,
      (__attribute__((address_space(3))) void*)l, 16, 0, 0);
}

// ---------------------------------------------------------------------------
struct Epi {
  const float* bias;
  const u16* r1; int r1Hp, r1pad, r1sh;   // residual adds (C=256 NHWC)
  const u16* r2; int r2Hp, r2pad, r2sh;
  const float* gamma; const u16* other; int oHp, opad, gmode; // 1: g*o+(1-g)*v ; 2: g*v+(1-g)*o
  u16* outB; int oBHp, oBpad, oBrelu;     // bf16 NHWC out (C=M)
  float* outF;                             // fp32 NCHW out
};

__device__ __forceinline__ size_t nhwc_idx(int b, int h, int w, int Hp, int pad, int Cc, int m) {
  return (((size_t)(b * Hp + h + pad)) * Hp + (w + pad)) * Cc + m;
}

__device__ __forceinline__ void epi_apply_store(float v, int m, int b, int oh, int ow,
                                                int p, int M, int l2ohow, float g, const Epi& ep) {
  if (ep.bias) v += ep.bias[m];
  if (ep.r1) v += bf2f(ep.r1[nhwc_idx(b, oh >> ep.r1sh, ow >> ep.r1sh, ep.r1Hp, ep.r1pad, 256, m)]);
  if (ep.r2) v += bf2f(ep.r2[nhwc_idx(b, oh >> ep.r2sh, ow >> ep.r2sh, ep.r2Hp, ep.r2pad, 256, m)]);
  if (ep.gmode) {
    float o = bf2f(ep.other[nhwc_idx(b, oh, ow, ep.oHp, ep.opad, 256, m)]);
    v = (ep.gmode == 1) ? (g * o + (1.f - g) * v) : (g * v + (1.f - g) * o);
  }
  if (ep.outF) ep.outF[(((size_t)(b * M + m)) << l2ohow) + p] = v;
  if (ep.outB) {
    float w = ep.oBrelu ? fmaxf(v, 0.f) : v;
    ep.outB[nhwc_idx(b, oh, ow, ep.oBHp, ep.oBpad, M, m)] = f2bf(w);
  }
}

// ---------------------------------------------------------------------------
// Weight convert/reorder fp32 OIHW -> bf16 [M][K'], k' = (kh*KW+kw)*Cin + c.
// mode1 (BA 1x1 on concat): k' = c*5 + g  (input channel = g*C + c).
// ---------------------------------------------------------------------------
struct WSeg { const float* src; u16* dst; int M, K, l2Cin, mode; };
struct WTab { WSeg s[17]; };

__global__ __launch_bounds__(256) void k_cvt_w(WTab tab) {
  WSeg sg = tab.s[blockIdx.y];
  int total = sg.M * sg.K;
  for (int o = blockIdx.x * 256 + threadIdx.x; o < total; o += gridDim.x * 256) {
    int m = o / sg.K, r = o - m * sg.K;
    int si;
    if (sg.mode == 1) {
      int C = sg.K / 5; int c = r / 5; int gq = r - c * 5;
      si = m * sg.K + gq * C + c;
    } else {
      int Cin = 1 << sg.l2Cin; int KHW = sg.K >> sg.l2Cin;
      int q = r >> sg.l2Cin; int c = r & (Cin - 1);
      si = (m * Cin + c) * KHW + q;
    }
    sg.dst[o] = f2bf(sg.src[si]);
  }
}

// ---------------------------------------------------------------------------
// NCHW fp32 -> NHWC bf16 (optional pad), LDS 32x32 transpose tiles.
// grid: x = (C/32)*tw, y = H, z = B
// ---------------------------------------------------------------------------
__global__ __launch_bounds__(256) void k_cvt_x(const float* __restrict__ in, u16* __restrict__ out,
                                               int C, int H, int W, int Hp, int P, int tw) {
  __shared__ u16 tile[32][33];
  const int t = threadIdx.x;
  const int b = blockIdx.z, h = blockIdx.y;
  const int tc = blockIdx.x / tw, twi = blockIdx.x - tc * tw;
  const int c0 = tc * 32, w0 = twi * 32;
#pragma unroll
  for (int r = 0; r < 4; ++r) {
    int cl = (t >> 5) * 4 + r, wl = t & 31;
    if (w0 + wl < W) tile[cl][wl] = f2bf(in[(((size_t)b * C + c0 + cl) * H + h) * W + w0 + wl]);
  }
  __syncthreads();
#pragma unroll
  for (int r = 0; r < 4; ++r) {
    int wl = (t >> 5) * 4 + r, cl = t & 31;
    if (w0 + wl < W) out[(((size_t)(b * Hp + h + P)) * Hp + (w0 + wl + P)) * C + c0 + cl] = tile[cl][wl];
  }
}

// ---------------------------------------------------------------------------
// Cummax scans -> interleaved cat NHWC bf16: channel j = c*5 + g,
// groups g: [x, prefH, sufH, prefW, sufW]. One block per (b,c) plane.
// ---------------------------------------------------------------------------
template<int S, int L2S>
__global__ __launch_bounds__(256) void k_scan(const float* __restrict__ x, u16* __restrict__ cat, int l2C) {
  __shared__ u16 pl[S][S + 1], cp[S][S + 1], cs[S][S + 1], rp[S][S + 1], rs[S][S + 1];
  const int pid = blockIdx.x;
  const int C = 1 << l2C;
  const int b = pid >> l2C, c = pid & (C - 1);
  const float* xp = x + (size_t)pid * (S * S);
  const int t = threadIdx.x;
  for (int idx = t; idx < S * S; idx += 256)
    pl[idx >> L2S][idx & (S - 1)] = f2bf(xp[idx]);
  __syncthreads();
  if (t < S) {
    float m = -INFINITY;
    for (int h = 0; h < S; ++h) { m = fmaxf(m, bf2f(pl[h][t])); cp[h][t] = f2bf(m); }
    m = -INFINITY;
    for (int h = S - 1; h >= 0; --h) { m = fmaxf(m, bf2f(pl[h][t])); cs[h][t] = f2bf(m); }
  } else if (t < 2 * S) {
    int h = t - S;
    float m = -INFINITY;
    for (int w = 0; w < S; ++w) { m = fmaxf(m, bf2f(pl[h][w])); rp[h][w] = f2bf(m); }
    m = -INFINITY;
    for (int w = S - 1; w >= 0; --w) { m = fmaxf(m, bf2f(pl[h][w])); rs[h][w] = f2bf(m); }
  }
  __syncthreads();
  const int C5v = 5 << l2C;
  for (int idx = t; idx < S * S; idx += 256) {
    int h = idx >> L2S, w = idx & (S - 1);
    u16* o = cat + ((size_t)((b * S + h) * S + w)) * C5v + c * 5;
    o[0] = pl[h][w]; o[1] = cp[h][w]; o[2] = cs[h][w]; o[3] = rp[h][w]; o[4] = rs[h][w];
  }
}

// ---------------------------------------------------------------------------
// bf16 MFMA implicit-GEMM conv. M=Cout, N=B*OH*OW, K=QDIV*Cin (k'=(kh,kw,c)).
// 128x128 tile, BK=32, 4 waves each 64x64 (4x4 frags of 16x16x32).
// LDS layout per operand: [kc=4][half=2][row=64][8] bf16.
// Staged with global_load_lds width 16. Input X is bf16 NHWC (padded; ipad
// shifts the window). FUSE: fused epilogue; else fp32 partials [z][M][N].
// ---------------------------------------------------------------------------
template<int QDIV, int KW, int STR, bool FUSE>
__global__ __launch_bounds__(256)
void k_gemm(const u16* __restrict__ X, const u16* __restrict__ Wt,
            float* __restrict__ part, int C, int l2C, int Hp, int ipad,
            int l2ohow, int l2ow, int K, int Ksp, int M, int N, Epi ep) {
  __shared__ u16 Al[4096];
  __shared__ u16 Bl[4096];
  const int tid = threadIdx.x, lane = tid & 63, wid = tid >> 6;
  const int n0 = blockIdx.x * 128, m0 = blockIdx.y * 128;
  const int kb = blockIdx.z * Ksp;
  const int mw = (wid >> 1) * 64, nw = (wid & 1) * 64;

  // A staging addresses (weights, rows m0+lane / m0+64+lane, k-chunk = wid*8)
  const u16* ga0 = Wt + (size_t)(m0 + lane) * K + kb + wid * 8;
  const u16* ga1 = ga0 + (size_t)64 * K;

  // B staging: pixel decode for rows n0+lane / n0+64+lane
  const u16* gb0 = nullptr; const u16* gb1 = nullptr;
  int bHp[2], ohs[2], ows[2];
#pragma unroll
  for (int i = 0; i < 2; ++i) {
    int n = n0 + i * 64 + lane;
    int b = n >> l2ohow, p = n & ((1 << l2ohow) - 1);
    int oh = p >> l2ow, ow = p & ((1 << l2ow) - 1);
    if (QDIV == 1) {
      const u16* gg = X + ((size_t)(b * Hp + oh + ipad) * Hp + (ow + ipad)) * C + kb + wid * 8;
      if (i == 0) gb0 = gg; else gb1 = gg;
    } else {
      bHp[i] = b * Hp; ohs[i] = oh * STR + ipad; ows[i] = ow * STR + ipad;
    }
  }

  f4v acc[4][4];
#pragma unroll
  for (int i = 0; i < 4; ++i)
#pragma unroll
    for (int j = 0; j < 4; ++j) acc[i][j] = (f4v){0.f, 0.f, 0.f, 0.f};

  u16* alb = &Al[wid * 1024];
  u16* blb = &Bl[wid * 1024];

  for (int ks = 0; ks < Ksp; ks += 32) {
    gload16(ga0, alb); gload16(ga1, alb + 512);
    ga0 += 32; ga1 += 32;
    if (QDIV == 1) {
      gload16(gb0, blb); gload16(gb1, blb + 512);
      gb0 += 32; gb1 += 32;
    } else {
      int k = kb + ks + wid * 8;
      int q = k >> l2C, c = k & (C - 1);
      int kh, kw;
      if (QDIV == 4) { kh = q >> 1; kw = q & 1; } else { kh = q / 3; kw = q - kh * 3; }
      const u16* g0 = X + ((size_t)(bHp[0] + ohs[0] + kh) * Hp + (ows[0] + kw)) * C + c;
      const u16* g1 = X + ((size_t)(bHp[1] + ohs[1] + kh) * Hp + (ows[1] + kw)) * C + c;
      gload16(g0, blb); gload16(g1, blb + 512);
    }
    __syncthreads();
    const int ar = (lane >> 4) * 1024, rl = (lane & 15) * 8;
    s8v a[4], bv[4];
#pragma unroll
    for (int mf = 0; mf < 4; ++mf) a[mf] = *(const s8v*)&Al[ar + mw * 8 + mf * 128 + rl];
#pragma unroll
    for (int nf = 0; nf < 4; ++nf) bv[nf] = *(const s8v*)&Bl[ar + nw * 8 + nf * 128 + rl];
#pragma unroll
    for (int mf = 0; mf < 4; ++mf)
#pragma unroll
      for (int nf = 0; nf < 4; ++nf)
        acc[mf][nf] = __builtin_amdgcn_mfma_f32_16x16x32_bf16(a[mf], bv[nf], acc[mf][nf], 0, 0, 0);
    __syncthreads();
  }

  const int r4 = (lane >> 4) * 4, cl = lane & 15;
  if (FUSE) {
    float g = ep.gmode ? *ep.gamma : 0.f;
#pragma unroll
    for (int nf = 0; nf < 4; ++nf) {
      int n = n0 + nw + nf * 16 + cl;
      int b = n >> l2ohow, p = n & ((1 << l2ohow) - 1);
      int oh = p >> l2ow, ow = p & ((1 << l2ow) - 1);
#pragma unroll
      for (int mf = 0; mf < 4; ++mf)
#pragma unroll
        for (int r = 0; r < 4; ++r) {
          int m = m0 + mw + mf * 16 + r4 + r;
          epi_apply_store(acc[mf][nf][r], m, b, oh, ow, p, M, l2ohow, g, ep);
        }
    }
  } else {
#pragma unroll
    for (int mf = 0; mf < 4; ++mf)
#pragma unroll
      for (int r = 0; r < 4; ++r) {
        int m = m0 + mw + mf * 16 + r4 + r;
        float* pr = part + ((size_t)blockIdx.z * M + m) * N + n0 + nw + cl;
#pragma unroll
        for (int nf = 0; nf < 4; ++nf) pr[nf * 16] = acc[mf][nf][r];
      }
  }
}

// ---------------------------------------------------------------------------
// Split-K reduce + epilogue. part: [z][M][N] fp32, N = 1<<l2N.
// ---------------------------------------------------------------------------
__global__ __launch_bounds__(256) void k_red(const float* __restrict__ part, int z, int M,
                                             int l2N, int l2ohow, int l2ow, Epi ep) {
  size_t MN = ((size_t)M) << l2N;
  int N = 1 << l2N;
  float g = ep.gmode ? *ep.gamma : 0.f;
  for (size_t e = (size_t)blockIdx.x * 256 + threadIdx.x; e < MN; e += (size_t)gridDim.x * 256) {
    float v = 0.f;
    for (int s = 0; s < z; ++s) v += part[(size_t)s * MN + e];
    int m = (int)(e >> l2N), n = (int)(e & (N - 1));
    int b = n >> l2ohow, p = n & ((1 << l2ohow) - 1);
    int oh = p >> l2ow, ow = p & ((1 << l2ow) - 1);
    epi_apply_store(v, m, b, oh, ow, p, M, l2ohow, g, ep);
  }
}

// ---------------------------------------------------------------------------
// ws layout (u16 element offsets).
// [weights 0..13.6M][persistent bf16 buffers 13.6M..70.4M][scratch 70.4M..112.3M]
// Scratch (cat/part/partba) NEVER overlaps persistent padded buffers, so the
// border-zero memsets done at launch start stay valid (round-2 bug fix).
// Total = 112,336,896 u16 = 224.7 MB (ws >= 226.5 MB per round-1 evidence).
// ---------------------------------------------------------------------------
static const size_t WR_BA3 = 0, WR_BA4 = 327680, WR_BA5 = 1638400,
  WR_P51 = 6881280, WR_P51D = 7143424, WR_P52 = 7405568, WR_P41 = 7995392,
  WR_P41D = 8126464, WR_P42 = 8257536, WR_P31 = 8847360, WR_P31D = 8912896,
  WR_P32 = 8978432, WR_P6 = 9568256, WR_P7 = 11927552, WR_C34 = 12517376,
  WR_C45 = 13107200, WR_C35 = 13369344;
static const size_t O_C3BA = 13631488, O_C4BA = 22020096, O_C5BA = 26214400,
  O_C3N = 28311552, O_C4N = 36700160, O_C5N = 40894464,
  O_P3D = 43548672, O_P3D1 = 52469760, O_P3D2 = 54566912,
  O_P4D = 55091200, O_P4D1 = 57188352, O_P5PRE = 57712640,
  O_P5S = 58376192, O_P4PRE = 58900480, O_P3PRE = 61267968, O_P6R = 70189056,
  O_SCR = 70393856;
static const size_t O_CAT = O_SCR, O_PART = O_SCR, O_PARTBA = O_SCR + 10485760;

extern "C" void kernel_launch(void* const* d_in, const int* in_sizes, int n_in,
                              void* d_out, int out_size, void* d_ws, size_t ws_size,
                              hipStream_t stream) {
  (void)in_sizes; (void)n_in; (void)out_size; (void)ws_size;
  const float* C3 = (const float*)d_in[0];
  const float* C4 = (const float*)d_in[1];
  const float* C5 = (const float*)d_in[2];
  const float* ba3_w = (const float*)d_in[3];  const float* ba3_b = (const float*)d_in[4];
  const float* ba4_w = (const float*)d_in[5];  const float* ba4_b = (const float*)d_in[6];
  const float* ba5_w = (const float*)d_in[7];  const float* ba5_b = (const float*)d_in[8];
  const float* p5_1_w = (const float*)d_in[9];  const float* p5_1_b = (const float*)d_in[10];
  const float* p5_1d_w = (const float*)d_in[11]; const float* p5_1d_b = (const float*)d_in[12];
  const float* p5_2_w = (const float*)d_in[13]; const float* p5_2_b = (const float*)d_in[14];
  const float* p4_1_w = (const float*)d_in[15]; const float* p4_1_b = (const float*)d_in[16];
  const float* p4_1d_w = (const float*)d_in[17]; const float* p4_1d_b = (const float*)d_in[18];
  const float* p4_2_w = (const float*)d_in[19]; const float* p4_2_b = (const float*)d_in[20];
  const float* p3_1_w = (const float*)d_in[21]; const float* p3_1_b = (const float*)d_in[22];
  const float* p3_1d_w = (const float*)d_in[23]; const float* p3_1d_b = (const float*)d_in[24];
  const float* p3_2_w = (const float*)d_in[25]; const float* p3_2_b = (const float*)d_in[26];
  const float* p6_w = (const float*)d_in[27]; const float* p6_b = (const float*)d_in[28];
  const float* p7_w = (const float*)d_in[29]; const float* p7_b = (const float*)d_in[30];
  const float* c34_w = (const float*)d_in[31]; const float* c34_b = (const float*)d_in[32];
  const float* c45_w = (const float*)d_in[33]; const float* c45_b = (const float*)d_in[34];
  const float* c35_w = (const float*)d_in[35]; const float* c35_b = (const float*)d_in[36];
  const float* g3 = (const float*)d_in[37];
  const float* g4 = (const float*)d_in[38];
  const float* g5 = (const float*)d_in[39];

  float* out = (float*)d_out;
  float* O3 = out;
  float* O4 = out + 8388608;
  float* O5 = out + 10485760;
  float* P6o = out + 11010048;
  float* P7o = out + 11141120;

  u16* wsu = (u16*)d_ws;
  u16* cat = wsu + O_CAT;
  u16* c3ba = wsu + O_C3BA; u16* c4ba = wsu + O_C4BA; u16* c5ba = wsu + O_C5BA;
  u16* c3n = wsu + O_C3N;  u16* c4n = wsu + O_C4N;  u16* c5n = wsu + O_C5N;
  u16* p3d = wsu + O_P3D;  u16* p3d1 = wsu + O_P3D1; u16* p3d2 = wsu + O_P3D2;
  u16* p4d = wsu + O_P4D;  u16* p4d1 = wsu + O_P4D1;
  u16* p5pre = wsu + O_P5PRE; u16* p5s = wsu + O_P5S; u16* p4pre = wsu + O_P4PRE;
  u16* p3pre = wsu + O_P3PRE; u16* p6r = wsu + O_P6R;
  float* part = (float*)(wsu + O_PART);
  float* partba = (float*)(wsu + O_PARTBA);

  const Epi enone = {nullptr, nullptr,0,0,0, nullptr,0,0,0, nullptr,nullptr,0,0,0, nullptr,0,0,0, nullptr};

  // ---- weight conversion (one kernel, 17 segments) ----
  WTab tab;
  int ti = 0;
  auto add = [&](const float* s, size_t off, int M, int K, int l2Cin, int mode) {
    tab.s[ti].src = s; tab.s[ti].dst = wsu + off; tab.s[ti].M = M; tab.s[ti].K = K;
    tab.s[ti].l2Cin = l2Cin; tab.s[ti].mode = mode; ++ti;
  };
  add(ba3_w, WR_BA3, 256, 1280, 0, 1);
  add(ba4_w, WR_BA4, 512, 2560, 0, 1);
  add(ba5_w, WR_BA5, 1024, 5120, 0, 1);
  add(p5_1_w, WR_P51, 256, 1024, 10, 0);
  add(p5_1d_w, WR_P51D, 256, 1024, 10, 0);
  add(p5_2_w, WR_P52, 256, 2304, 8, 0);
  add(p4_1_w, WR_P41, 256, 512, 9, 0);
  add(p4_1d_w, WR_P41D, 256, 512, 9, 0);
  add(p4_2_w, WR_P42, 256, 2304, 8, 0);
  add(p3_1_w, WR_P31, 256, 256, 8, 0);
  add(p3_1d_w, WR_P31D, 256, 256, 8, 0);
  add(p3_2_w, WR_P32, 256, 2304, 8, 0);
  add(p6_w, WR_P6, 256, 9216, 10, 0);
  add(p7_w, WR_P7, 256, 2304, 8, 0);
  add(c34_w, WR_C34, 256, 2304, 8, 0);
  add(c45_w, WR_C45, 256, 1024, 8, 0);
  add(c35_w, WR_C35, 256, 1024, 8, 0);
  k_cvt_w<<<dim3(96, 17), 256, 0, stream>>>(tab);

  // ---- zero padded buffers (borders persist: scratch never overlaps them) ----
  hipMemsetAsync(c5n, 0, (size_t)2654208 * 2, stream);
  hipMemsetAsync(p3d, 0, (size_t)8921088 * 2, stream);
  hipMemsetAsync(p5pre, 0, (size_t)663552 * 2, stream);
  hipMemsetAsync(p4pre, 0, (size_t)2367488 * 2, stream);
  hipMemsetAsync(p3pre, 0, (size_t)8921088 * 2, stream);
  hipMemsetAsync(p6r, 0, (size_t)204800 * 2, stream);

  // ================= BA phase (cat scratch) =================
  k_scan<64, 6><<<2048, 256, 0, stream>>>(C3, cat, 8);
  {
    Epi ep = {ba3_b, nullptr,0,0,0, nullptr,0,0,0, nullptr,nullptr,0,0,0, c3ba,64,0,0, nullptr};
    k_gemm<1,1,1,true><<<dim3(256,2,1), 256, 0, stream>>>(
        cat, wsu + WR_BA3, nullptr, 1280, 0, 64, 0, 12, 6, 1280, 1280, 256, 32768, ep);
  }
  k_scan<32, 5><<<4096, 256, 0, stream>>>(C4, cat, 9);
  {
    Epi ep = {ba4_b, nullptr,0,0,0, nullptr,0,0,0, nullptr,nullptr,0,0,0, c4ba,32,0,0, nullptr};
    k_gemm<1,1,1,true><<<dim3(64,4,1), 256, 0, stream>>>(
        cat, wsu + WR_BA4, nullptr, 2560, 0, 32, 0, 10, 5, 2560, 2560, 512, 8192, ep);
  }
  k_scan<16, 4><<<8192, 256, 0, stream>>>(C5, cat, 10);
  k_gemm<1,1,1,false><<<dim3(16,8,2), 256, 0, stream>>>(
      cat, wsu + WR_BA5, partba, 5120, 0, 16, 0, 8, 4, 5120, 2560, 1024, 2048, enone);
  {
    Epi ep = {ba5_b, nullptr,0,0,0, nullptr,0,0,0, nullptr,nullptr,0,0,0, c5ba,16,0,0, nullptr};
    k_red<<<2048, 256, 0, stream>>>(partba, 2, 1024, 11, 8, 4, ep);
  }

  // ---- input conversions ----
  k_cvt_x<<<dim3(16,64,8), 256, 0, stream>>>(C3, c3n, 256, 64, 64, 64, 0, 2);
  k_cvt_x<<<dim3(16,32,8), 256, 0, stream>>>(C4, c4n, 512, 32, 32, 32, 0, 1);
  k_cvt_x<<<dim3(32,16,8), 256, 0, stream>>>(C5, c5n, 1024, 16, 16, 18, 1, 1);

  // ================= dual (bottom-up) path =================
  {
    Epi ep = {p3_1d_b, nullptr,0,0,0, nullptr,0,0,0, nullptr,nullptr,0,0,0, p3d,66,1,0, nullptr};
    k_gemm<1,1,1,true><<<dim3(256,2,1), 256, 0, stream>>>(
        c3ba, wsu + WR_P31D, nullptr, 256, 0, 64, 0, 12, 6, 256, 256, 256, 32768, ep);
  }
  k_gemm<9,3,2,false><<<dim3(64,2,2), 256, 0, stream>>>(
      p3d, wsu + WR_C34, part, 256, 8, 66, 0, 10, 5, 2304, 1152, 256, 8192, enone);
  {
    Epi ep = {c34_b, nullptr,0,0,0, nullptr,0,0,0, nullptr,nullptr,0,0,0, p3d1,32,0,0, nullptr};
    k_red<<<2048, 256, 0, stream>>>(part, 2, 256, 13, 10, 5, ep);
  }
  k_gemm<4,2,2,false><<<dim3(16,2,8), 256, 0, stream>>>(
      p3d1, wsu + WR_C35, part, 256, 8, 32, 0, 8, 4, 1024, 128, 256, 2048, enone);
  {
    Epi ep = {c35_b, nullptr,0,0,0, nullptr,0,0,0, nullptr,nullptr,0,0,0, p3d2,16,0,0, nullptr};
    k_red<<<2048, 256, 0, stream>>>(part, 8, 256, 11, 8, 4, ep);
  }
  k_gemm<1,1,1,false><<<dim3(64,2,2), 256, 0, stream>>>(
      c4ba, wsu + WR_P41D, part, 512, 0, 32, 0, 10, 5, 512, 256, 256, 8192, enone);
  {
    Epi ep = {p4_1d_b, p3d1,32,0,0, nullptr,0,0,0, nullptr,nullptr,0,0,0, p4d,32,0,0, nullptr};
    k_red<<<2048, 256, 0, stream>>>(part, 2, 256, 13, 10, 5, ep);
  }
  k_gemm<4,2,2,false><<<dim3(16,2,8), 256, 0, stream>>>(
      p4d, wsu + WR_C45, part, 256, 8, 32, 0, 8, 4, 1024, 128, 256, 2048, enone);
  {
    Epi ep = {c45_b, nullptr,0,0,0, nullptr,0,0,0, nullptr,nullptr,0,0,0, p4d1,16,0,0, nullptr};
    k_red<<<2048, 256, 0, stream>>>(part, 8, 256, 11, 8, 4, ep);
  }

  // ================= top-down path =================
  k_gemm<1,1,1,false><<<dim3(16,2,8), 256, 0, stream>>>(
      c5n, wsu + WR_P51, part, 1024, 0, 18, 1, 8, 4, 1024, 128, 256, 2048, enone);
  {
    Epi ep = {p5_1_b, nullptr,0,0,0, nullptr,0,0,0, nullptr,nullptr,0,0,0, p5pre,18,1,0, nullptr};
    k_red<<<2048, 256, 0, stream>>>(part, 8, 256, 11, 8, 4, ep);
  }
  k_gemm<9,3,1,false><<<dim3(16,2,8), 256, 0, stream>>>(
      p5pre, wsu + WR_P52, part, 256, 8, 18, 0, 8, 4, 2304, 288, 256, 2048, enone);
  {
    Epi ep = {p5_2_b, nullptr,0,0,0, nullptr,0,0,0, nullptr,nullptr,0,0,0, p5s,16,0,0, nullptr};
    k_red<<<2048, 256, 0, stream>>>(part, 8, 256, 11, 8, 4, ep);
  }
  k_gemm<1,1,1,false><<<dim3(64,2,2), 256, 0, stream>>>(
      c4n, wsu + WR_P41, part, 512, 0, 32, 0, 10, 5, 512, 256, 256, 8192, enone);
  {
    Epi ep = {p4_1_b, p5pre,18,1,1, nullptr,0,0,0, nullptr,nullptr,0,0,0, p4pre,34,1,0, nullptr};
    k_red<<<2048, 256, 0, stream>>>(part, 2, 256, 13, 10, 5, ep);
  }
  k_gemm<9,3,1,false><<<dim3(64,2,2), 256, 0, stream>>>(
      p4pre, wsu + WR_P42, part, 256, 8, 34, 0, 10, 5, 2304, 1152, 256, 8192, enone);
  {
    Epi ep = {p4_2_b, nullptr,0,0,0, nullptr,0,0,0, g4,p4d,32,0,1, nullptr,0,0,0, O4};
    k_red<<<2048, 256, 0, stream>>>(part, 2, 256, 13, 10, 5, ep);
  }
  {
    Epi ep = {p3_1_b, p4pre,34,1,1, p5pre,18,1,2, nullptr,nullptr,0,0,0, p3pre,66,1,0, nullptr};
    k_gemm<1,1,1,true><<<dim3(256,2,1), 256, 0, stream>>>(
        c3n, wsu + WR_P31, nullptr, 256, 0, 64, 0, 12, 6, 256, 256, 256, 32768, ep);
  }
  {
    Epi ep = {p3_2_b, nullptr,0,0,0, nullptr,0,0,0, g3,p3d,66,1,1, nullptr,0,0,0, O3};
    k_gemm<9,3,1,true><<<dim3(256,2,1), 256, 0, stream>>>(
        p3pre, wsu + WR_P32, nullptr, 256, 8, 66, 0, 12, 6, 2304, 2304, 256, 32768, ep);
  }
  k_gemm<1,1,1,false><<<dim3(16,2,8), 256, 0, stream>>>(
      c5ba, wsu + WR_P51D, part, 1024, 0, 16, 0, 8, 4, 1024, 128, 256, 2048, enone);
  {
    Epi ep = {p5_1d_b, p4d1,16,0,0, p3d2,16,0,0, g5,p5s,16,0,2, nullptr,0,0,0, O5};
    k_red<<<2048, 256, 0, stream>>>(part, 8, 256, 11, 8, 4, ep);
  }

  // ================= P6 / P7 =================
  k_gemm<9,3,2,false><<<dim3(4,2,16), 256, 0, stream>>>(
      c5n, wsu + WR_P6, part, 1024, 10, 18, 0, 6, 3, 9216, 576, 256, 512, enone);
  {
    Epi ep = {p6_b, nullptr,0,0,0, nullptr,0,0,0, nullptr,nullptr,0,0,0, p6r,10,1,1, P6o};
    k_red<<<512, 256, 0, stream>>>(part, 16, 256, 9, 6, 3, ep);
  }
  k_gemm<9,3,2,false><<<dim3(1,2,8), 256, 0, stream>>>(
      p6r, wsu + WR_P7, part, 256, 8, 10, 0, 4, 2, 2304, 288, 256, 128, enone);
  {
    Epi ep = {p7_b, nullptr,0,0,0, nullptr,0,0,0, nullptr,nullptr,0,0,0, nullptr,0,0,0, P7o};
    k_red<<<128, 256, 0, stream>>>(part, 8, 256, 7, 4, 2, ep);
  }
}

// Round 4
// 1154.226 us; speedup vs baseline: 2.3267x; 1.1272x over previous
//
#include <hip/hip_runtime.h>

typedef unsigned short u16;
typedef __attribute__((ext_vector_type(8))) short s8v;
typedef __attribute__((ext_vector_type(4))) float f4v;

__device__ __forceinline__ u16 f2bf(float f) {
  unsigned int x = __float_as_uint(f);
  return (u16)((x + 0x7fffu + ((x >> 16) & 1u)) >> 16);
}
__device__ __forceinline__ float bf2f(u16 u) {
  return __uint_as_float(((unsigned int)u) << 16);
}
__device__ __forceinline__ void gload16(const void* g, void* l) {
  __builtin_amdgcn_global_load_lds(
      (const __attribute__((address_space(1))) void*)g,
      (__attribute__((address_space(3))) void*)l, 16, 0, 0);
}

// ---------------------------------------------------------------------------
struct Epi {
  const float* bias;
  const u16* r1; int r1Hp, r1pad, r1sh;   // residual adds (C=256 NHWC)
  const u16* r2; int r2Hp, r2pad, r2sh;
  const float* gamma; const u16* other; int oHp, opad, gmode; // 1: g*o+(1-g)*v ; 2: g*v+(1-g)*o
  u16* outB; int oBHp, oBpad, oBrelu;     // bf16 NHWC out (C=M)
  float* outF;                             // fp32 NCHW out
};

__device__ __forceinline__ size_t nhwc_idx(int b, int h, int w, int Hp, int pad, int Cc, int m) {
  return (((size_t)(b * Hp + h + pad)) * Hp + (w + pad)) * Cc + m;
}

__device__ __forceinline__ void epi_apply_store(float v, int m, int b, int oh, int ow,
                                                int p, int M, int l2ohow, float g, const Epi& ep) {
  if (ep.bias) v += ep.bias[m];
  if (ep.r1) v += bf2f(ep.r1[nhwc_idx(b, oh >> ep.r1sh, ow >> ep.r1sh, ep.r1Hp, ep.r1pad, 256, m)]);
  if (ep.r2) v += bf2f(ep.r2[nhwc_idx(b, oh >> ep.r2sh, ow >> ep.r2sh, ep.r2Hp, ep.r2pad, 256, m)]);
  if (ep.gmode) {
    float o = bf2f(ep.other[nhwc_idx(b, oh, ow, ep.oHp, ep.opad, 256, m)]);
    v = (ep.gmode == 1) ? (g * o + (1.f - g) * v) : (g * v + (1.f - g) * o);
  }
  if (ep.outF) ep.outF[(((size_t)(b * M + m)) << l2ohow) + p] = v;
  if (ep.outB) {
    float w = ep.oBrelu ? fmaxf(v, 0.f) : v;
    ep.outB[nhwc_idx(b, oh, ow, ep.oBHp, ep.oBpad, M, m)] = f2bf(w);
  }
}

// ---------------------------------------------------------------------------
// Weight convert/reorder fp32 OIHW -> bf16 [M][K'], k' = (kh*KW+kw)*Cin + c.
// mode1 (BA convs): dst k' = g*C + c with new group order
//   g=0..3 -> [prefH, sufH, prefW, sufW] (orig groups 1..4), g=4 -> x (orig 0).
// ---------------------------------------------------------------------------
struct WSeg { const float* src; u16* dst; int M, K, l2Cin, mode; };
struct WTab { WSeg s[17]; };

__global__ __launch_bounds__(256) void k_cvt_w(WTab tab) {
  WSeg sg = tab.s[blockIdx.y];
  int total = sg.M * sg.K;
  for (int o = blockIdx.x * 256 + threadIdx.x; o < total; o += gridDim.x * 256) {
    int m = o / sg.K, r = o - m * sg.K;
    int si;
    if (sg.mode == 1) {
      int C = sg.K / 5; int g = r / C; int c = r - g * C;
      int og = (g < 4) ? (g + 1) : 0;
      si = m * sg.K + og * C + c;
    } else {
      int Cin = 1 << sg.l2Cin; int KHW = sg.K >> sg.l2Cin;
      int q = r >> sg.l2Cin; int c = r & (Cin - 1);
      si = (m * Cin + c) * KHW + q;
    }
    sg.dst[o] = f2bf(sg.src[si]);
  }
}

// ---------------------------------------------------------------------------
// NCHW fp32 -> NHWC bf16 (optional pad), LDS 32x32 transpose tiles.
// grid: x = (C/32)*tw, y = H, z = B
// ---------------------------------------------------------------------------
__global__ __launch_bounds__(256) void k_cvt_x(const float* __restrict__ in, u16* __restrict__ out,
                                               int C, int H, int W, int Hp, int P, int tw) {
  __shared__ u16 tile[32][33];
  const int t = threadIdx.x;
  const int b = blockIdx.z, h = blockIdx.y;
  const int tc = blockIdx.x / tw, twi = blockIdx.x - tc * tw;
  const int c0 = tc * 32, w0 = twi * 32;
#pragma unroll
  for (int r = 0; r < 4; ++r) {
    int cl = (t >> 5) * 4 + r, wl = t & 31;
    if (w0 + wl < W) tile[cl][wl] = f2bf(in[(((size_t)b * C + c0 + cl) * H + h) * W + w0 + wl]);
  }
  __syncthreads();
#pragma unroll
  for (int r = 0; r < 4; ++r) {
    int wl = (t >> 5) * 4 + r, cl = t & 31;
    if (w0 + wl < W) out[(((size_t)(b * Hp + h + P)) * Hp + (w0 + wl + P)) * C + c0 + cl] = tile[cl][wl];
  }
}

// ---------------------------------------------------------------------------
// Cummax scans, coalesced NCHW bf16 output: out[g][b*C+c][S*S], g=0..3 =
// [prefH, sufH, prefW, sufW]. One block per (b,c) plane; H-scans write
// directly (coalesced across columns), W-scans stage in LDS then copy out.
// ---------------------------------------------------------------------------
template<int S, int L2S>
__global__ __launch_bounds__(256) void k_scan2(const float* __restrict__ x,
                                               u16* __restrict__ out, int l2C) {
  __shared__ u16 pl[S][S + 1], rp[S][S + 1], rs[S][S + 1];
  const int pid = blockIdx.x;            // b*C + c
  const size_t SS = (size_t)S * S;
  const size_t GS = ((size_t)8 << l2C) * SS;
  const float* xp = x + (size_t)pid * SS;
  u16* g0 = out + (size_t)pid * SS;
  u16* g1 = g0 + GS;
  u16* g2 = g1 + GS;
  u16* g3 = g2 + GS;
  const int t = threadIdx.x;
  for (int idx = t; idx < S * S; idx += 256)
    pl[idx >> L2S][idx & (S - 1)] = f2bf(xp[idx]);
  __syncthreads();
  if (t < S) {
    float m = -INFINITY;
    for (int h = 0; h < S; ++h) { m = fmaxf(m, bf2f(pl[h][t])); g0[h * S + t] = f2bf(m); }
  } else if (t < 2 * S) {
    int c = t - S;
    float m = -INFINITY;
    for (int h = S - 1; h >= 0; --h) { m = fmaxf(m, bf2f(pl[h][c])); g1[h * S + c] = f2bf(m); }
  } else if (t < 3 * S) {
    int h = t - 2 * S;
    float m = -INFINITY;
    for (int w = 0; w < S; ++w) { m = fmaxf(m, bf2f(pl[h][w])); rp[h][w] = f2bf(m); }
  } else if (t < 4 * S) {
    int h = t - 3 * S;
    float m = -INFINITY;
    for (int w = S - 1; w >= 0; --w) { m = fmaxf(m, bf2f(pl[h][w])); rs[h][w] = f2bf(m); }
  }
  __syncthreads();
  for (int idx = t; idx < S * S; idx += 256) {
    g2[idx] = rp[idx >> L2S][idx & (S - 1)];
    g3[idx] = rs[idx >> L2S][idx & (S - 1)];
  }
}

// ---------------------------------------------------------------------------
// bf16 NCHW -> NHWC transpose (per group-batch plane set).
// src[z][C][S*S] -> dst[z][S*S][C], z = g*8 + b. grid: x=(C/32)*tw, y=S, z=4*8.
// ---------------------------------------------------------------------------
__global__ __launch_bounds__(256) void k_tr(const u16* __restrict__ src, u16* __restrict__ dst,
                                            int C, int S, int tw) {
  __shared__ u16 tile[32][33];
  const int t = threadIdx.x;
  const int z = blockIdx.z, h = blockIdx.y;
  const int tc = blockIdx.x / tw, twi = blockIdx.x - tc * tw;
  const int c0 = tc * 32, w0 = twi * 32;
  const size_t SS = (size_t)S * S;
  const u16* sp = src + (size_t)z * C * SS;
  u16* dp = dst + (size_t)z * SS * C;
#pragma unroll
  for (int r = 0; r < 4; ++r) {
    int cl = (t >> 5) * 4 + r, wl = t & 31;
    if (w0 + wl < S) tile[cl][wl] = sp[(size_t)(c0 + cl) * SS + h * S + w0 + wl];
  }
  __syncthreads();
#pragma unroll
  for (int r = 0; r < 4; ++r) {
    int wl = (t >> 5) * 4 + r, cl = t & 31;
    if (w0 + wl < S) dp[((size_t)(h * S + w0 + wl)) * C + c0 + cl] = tile[cl][wl];
  }
}

// ---------------------------------------------------------------------------
// bf16 MFMA implicit-GEMM conv. M=Cout, N=B*OH*OW, K per mode.
// QDIV==1: 1x1 conv, X NHWC (Hp/ipad window). QDIV==4/9: 2x2/3x3 conv.
// QDIV==5: BA group mode — K=5C, k=(g,c); g<4 reads CAT tensor g (X base,
// group stride (1<<Hp)<<l2C where Hp carries l2BHW), g==4 reads X2 (NHWC x).
// 128x128 tile, BK=32, 4 waves each 64x64 (4x4 frags of 16x16x32).
// ---------------------------------------------------------------------------
template<int QDIV, int KW, int STR, bool FUSE>
__global__ __launch_bounds__(256)
void k_gemm(const u16* __restrict__ X, const u16* __restrict__ X2,
            const u16* __restrict__ Wt,
            float* __restrict__ part, int C, int l2C, int Hp, int ipad,
            int l2ohow, int l2ow, int K, int Ksp, int M, int N, Epi ep) {
  __shared__ u16 Al[4096];
  __shared__ u16 Bl[4096];
  const int tid = threadIdx.x, lane = tid & 63, wid = tid >> 6;
  const int n0 = blockIdx.x * 128, m0 = blockIdx.y * 128;
  const int kb = blockIdx.z * Ksp;
  const int mw = (wid >> 1) * 64, nw = (wid & 1) * 64;

  // A staging addresses (weights, rows m0+lane / m0+64+lane, k-chunk = wid*8)
  const u16* ga0 = Wt + (size_t)(m0 + lane) * K + kb + wid * 8;
  const u16* ga1 = ga0 + (size_t)64 * K;

  // B staging: pixel decode for rows n0+lane / n0+64+lane
  const u16* gb0 = nullptr; const u16* gb1 = nullptr;
  int bHp[2], ohs[2], ows[2];
#pragma unroll
  for (int i = 0; i < 2; ++i) {
    int n = n0 + i * 64 + lane;
    int b = n >> l2ohow, p = n & ((1 << l2ohow) - 1);
    int oh = p >> l2ow, ow = p & ((1 << l2ow) - 1);
    if (QDIV == 1) {
      const u16* gg = X + ((size_t)(b * Hp + oh + ipad) * Hp + (ow + ipad)) * C + kb + wid * 8;
      if (i == 0) gb0 = gg; else gb1 = gg;
    } else if (QDIV == 5) {
      bHp[i] = n;                       // pixel linear index
    } else {
      bHp[i] = b * Hp; ohs[i] = oh * STR + ipad; ows[i] = ow * STR + ipad;
    }
  }

  f4v acc[4][4];
#pragma unroll
  for (int i = 0; i < 4; ++i)
#pragma unroll
    for (int j = 0; j < 4; ++j) acc[i][j] = (f4v){0.f, 0.f, 0.f, 0.f};

  u16* alb = &Al[wid * 1024];
  u16* blb = &Bl[wid * 1024];

  for (int ks = 0; ks < Ksp; ks += 32) {
    gload16(ga0, alb); gload16(ga1, alb + 512);
    ga0 += 32; ga1 += 32;
    if (QDIV == 1) {
      gload16(gb0, blb); gload16(gb1, blb + 512);
      gb0 += 32; gb1 += 32;
    } else if (QDIV == 5) {
      int k = kb + ks + wid * 8;
      int g = k >> l2C, c = k & (C - 1);
      const u16* base = (g < 4) ? (X + (((size_t)g << Hp) << l2C)) : X2;
      const u16* g0 = base + (((size_t)bHp[0]) << l2C) + c;
      const u16* g1 = base + (((size_t)bHp[1]) << l2C) + c;
      gload16(g0, blb); gload16(g1, blb + 512);
    } else {
      int k = kb + ks + wid * 8;
      int q = k >> l2C, c = k & (C - 1);
      int kh, kw;
      if (QDIV == 4) { kh = q >> 1; kw = q & 1; } else { kh = q / 3; kw = q - kh * 3; }
      const u16* g0 = X + ((size_t)(bHp[0] + ohs[0] + kh) * Hp + (ows[0] + kw)) * C + c;
      const u16* g1 = X + ((size_t)(bHp[1] + ohs[1] + kh) * Hp + (ows[1] + kw)) * C + c;
      gload16(g0, blb); gload16(g1, blb + 512);
    }
    __syncthreads();
    const int ar = (lane >> 4) * 1024, rl = (lane & 15) * 8;
    s8v a[4], bv[4];
#pragma unroll
    for (int mf = 0; mf < 4; ++mf) a[mf] = *(const s8v*)&Al[ar + mw * 8 + mf * 128 + rl];
#pragma unroll
    for (int nf = 0; nf < 4; ++nf) bv[nf] = *(const s8v*)&Bl[ar + nw * 8 + nf * 128 + rl];
#pragma unroll
    for (int mf = 0; mf < 4; ++mf)
#pragma unroll
      for (int nf = 0; nf < 4; ++nf)
        acc[mf][nf] = __builtin_amdgcn_mfma_f32_16x16x32_bf16(a[mf], bv[nf], acc[mf][nf], 0, 0, 0);
    __syncthreads();
  }

  const int r4 = (lane >> 4) * 4, cl = lane & 15;
  if (FUSE) {
    float g = ep.gmode ? *ep.gamma : 0.f;
#pragma unroll
    for (int nf = 0; nf < 4; ++nf) {
      int n = n0 + nw + nf * 16 + cl;
      int b = n >> l2ohow, p = n & ((1 << l2ohow) - 1);
      int oh = p >> l2ow, ow = p & ((1 << l2ow) - 1);
#pragma unroll
      for (int mf = 0; mf < 4; ++mf)
#pragma unroll
        for (int r = 0; r < 4; ++r) {
          int m = m0 + mw + mf * 16 + r4 + r;
          epi_apply_store(acc[mf][nf][r], m, b, oh, ow, p, M, l2ohow, g, ep);
        }
    }
  } else {
#pragma unroll
    for (int mf = 0; mf < 4; ++mf)
#pragma unroll
      for (int r = 0; r < 4; ++r) {
        int m = m0 + mw + mf * 16 + r4 + r;
        float* pr = part + ((size_t)blockIdx.z * M + m) * N + n0 + nw + cl;
#pragma unroll
        for (int nf = 0; nf < 4; ++nf) pr[nf * 16] = acc[mf][nf][r];
      }
  }
}

// ---------------------------------------------------------------------------
// Split-K reduce + epilogue. part: [z][M][N] fp32, N = 1<<l2N.
// ---------------------------------------------------------------------------
__global__ __launch_bounds__(256) void k_red(const float* __restrict__ part, int z, int M,
                                             int l2N, int l2ohow, int l2ow, Epi ep) {
  size_t MN = ((size_t)M) << l2N;
  int N = 1 << l2N;
  float g = ep.gmode ? *ep.gamma : 0.f;
  for (size_t e = (size_t)blockIdx.x * 256 + threadIdx.x; e < MN; e += (size_t)gridDim.x * 256) {
    float v = 0.f;
    for (int s = 0; s < z; ++s) v += part[(size_t)s * MN + e];
    int m = (int)(e >> l2N), n = (int)(e & (N - 1));
    int b = n >> l2ohow, p = n & ((1 << l2ohow) - 1);
    int oh = p >> l2ow, ow = p & ((1 << l2ow) - 1);
    epi_apply_store(v, m, b, oh, ow, p, M, l2ohow, g, ep);
  }
}

// ---------------------------------------------------------------------------
// ws layout (u16 element offsets). Total 110,100,480 u16 = 220.2 MB.
// [weights][c3n c4n c5n][c3ba c4ba c5ba][CAT 33.5M][SCR 33.5M]
// CAT: holds cum-group NHWC tensors during BA phase (L3 full, then L4, L5),
// then is reused for all post-BA persistents (memsets issued after BA).
// SCR: scan NCHW scratch during BA; split-K fp32 partials afterwards.
// ---------------------------------------------------------------------------
static const size_t WR_BA3 = 0, WR_BA4 = 327680, WR_BA5 = 1638400,
  WR_P51 = 6881280, WR_P51D = 7143424, WR_P52 = 7405568, WR_P41 = 7995392,
  WR_P41D = 8126464, WR_P42 = 8257536, WR_P31 = 8847360, WR_P31D = 8912896,
  WR_P32 = 8978432, WR_P6 = 9568256, WR_P7 = 11927552, WR_C34 = 12517376,
  WR_C45 = 13107200, WR_C35 = 13369344;
static const size_t O_C3N = 13631488, O_C4N = 22020096, O_C5N = 26214400,
  O_C3BA = 28311552, O_C4BA = 36700160, O_C5BA = 40894464,
  O_CAT = 42991616, O_SCR = 76546048;
static const size_t O_P3D = O_CAT, O_P3PRE = O_CAT + 8921088,
  O_P4PRE = O_CAT + 17842176, O_P3D1 = O_CAT + 20209664,
  O_P4D = O_CAT + 22306816, O_P4D1 = O_CAT + 24403968,
  O_P3D2 = O_CAT + 24928256, O_P5PRE = O_CAT + 25452544,
  O_P5S = O_CAT + 26116096, O_P6R = O_CAT + 26640384, O_C5P = O_CAT + 26845184;

extern "C" void kernel_launch(void* const* d_in, const int* in_sizes, int n_in,
                              void* d_out, int out_size, void* d_ws, size_t ws_size,
                              hipStream_t stream) {
  (void)in_sizes; (void)n_in; (void)out_size; (void)ws_size;
  const float* C3 = (const float*)d_in[0];
  const float* C4 = (const float*)d_in[1];
  const float* C5 = (const float*)d_in[2];
  const float* ba3_w = (const float*)d_in[3];  const float* ba3_b = (const float*)d_in[4];
  const float* ba4_w = (const float*)d_in[5];  const float* ba4_b = (const float*)d_in[6];
  const float* ba5_w = (const float*)d_in[7];  const float* ba5_b = (const float*)d_in[8];
  const float* p5_1_w = (const float*)d_in[9];  const float* p5_1_b = (const float*)d_in[10];
  const float* p5_1d_w = (const float*)d_in[11]; const float* p5_1d_b = (const float*)d_in[12];
  const float* p5_2_w = (const float*)d_in[13]; const float* p5_2_b = (const float*)d_in[14];
  const float* p4_1_w = (const float*)d_in[15]; const float* p4_1_b = (const float*)d_in[16];
  const float* p4_1d_w = (const float*)d_in[17]; const float* p4_1d_b = (const float*)d_in[18];
  const float* p4_2_w = (const float*)d_in[19]; const float* p4_2_b = (const float*)d_in[20];
  const float* p3_1_w = (const float*)d_in[21]; const float* p3_1_b = (const float*)d_in[22];
  const float* p3_1d_w = (const float*)d_in[23]; const float* p3_1d_b = (const float*)d_in[24];
  const float* p3_2_w = (const float*)d_in[25]; const float* p3_2_b = (const float*)d_in[26];
  const float* p6_w = (const float*)d_in[27]; const float* p6_b = (const float*)d_in[28];
  const float* p7_w = (const float*)d_in[29]; const float* p7_b = (const float*)d_in[30];
  const float* c34_w = (const float*)d_in[31]; const float* c34_b = (const float*)d_in[32];
  const float* c45_w = (const float*)d_in[33]; const float* c45_b = (const float*)d_in[34];
  const float* c35_w = (const float*)d_in[35]; const float* c35_b = (const float*)d_in[36];
  const float* g3 = (const float*)d_in[37];
  const float* g4 = (const float*)d_in[38];
  const float* g5 = (const float*)d_in[39];

  float* out = (float*)d_out;
  float* O3 = out;
  float* O4 = out + 8388608;
  float* O5 = out + 10485760;
  float* P6o = out + 11010048;
  float* P7o = out + 11141120;

  u16* wsu = (u16*)d_ws;
  u16* c3n = wsu + O_C3N;  u16* c4n = wsu + O_C4N;  u16* c5n = wsu + O_C5N;
  u16* c3ba = wsu + O_C3BA; u16* c4ba = wsu + O_C4BA; u16* c5ba = wsu + O_C5BA;
  u16* catb = wsu + O_CAT;
  u16* scr = wsu + O_SCR;
  u16* p3d = wsu + O_P3D;  u16* p3d1 = wsu + O_P3D1; u16* p3d2 = wsu + O_P3D2;
  u16* p4d = wsu + O_P4D;  u16* p4d1 = wsu + O_P4D1;
  u16* p5pre = wsu + O_P5PRE; u16* p5s = wsu + O_P5S; u16* p4pre = wsu + O_P4PRE;
  u16* p3pre = wsu + O_P3PRE; u16* p6r = wsu + O_P6R; u16* c5p = wsu + O_C5P;
  float* part = (float*)scr;
  float* partba = (float*)scr;

  const Epi enone = {nullptr, nullptr,0,0,0, nullptr,0,0,0, nullptr,nullptr,0,0,0, nullptr,0,0,0, nullptr};

  // ---- weight conversion ----
  WTab tab;
  int ti = 0;
  auto add = [&](const float* s, size_t off, int M, int K, int l2Cin, int mode) {
    tab.s[ti].src = s; tab.s[ti].dst = wsu + off; tab.s[ti].M = M; tab.s[ti].K = K;
    tab.s[ti].l2Cin = l2Cin; tab.s[ti].mode = mode; ++ti;
  };
  add(ba3_w, WR_BA3, 256, 1280, 0, 1);
  add(ba4_w, WR_BA4, 512, 2560, 0, 1);
  add(ba5_w, WR_BA5, 1024, 5120, 0, 1);
  add(p5_1_w, WR_P51, 256, 1024, 10, 0);
  add(p5_1d_w, WR_P51D, 256, 1024, 10, 0);
  add(p5_2_w, WR_P52, 256, 2304, 8, 0);
  add(p4_1_w, WR_P41, 256, 512, 9, 0);
  add(p4_1d_w, WR_P41D, 256, 512, 9, 0);
  add(p4_2_w, WR_P42, 256, 2304, 8, 0);
  add(p3_1_w, WR_P31, 256, 256, 8, 0);
  add(p3_1d_w, WR_P31D, 256, 256, 8, 0);
  add(p3_2_w, WR_P32, 256, 2304, 8, 0);
  add(p6_w, WR_P6, 256, 9216, 10, 0);
  add(p7_w, WR_P7, 256, 2304, 8, 0);
  add(c34_w, WR_C34, 256, 2304, 8, 0);
  add(c45_w, WR_C45, 256, 1024, 8, 0);
  add(c35_w, WR_C35, 256, 1024, 8, 0);
  k_cvt_w<<<dim3(96, 17), 256, 0, stream>>>(tab);

  // ---- input NHWC conversions (unpadded; group-x tensors for BA) ----
  k_cvt_x<<<dim3(16,64,8), 256, 0, stream>>>(C3, c3n, 256, 64, 64, 64, 0, 2);
  k_cvt_x<<<dim3(16,32,8), 256, 0, stream>>>(C4, c4n, 512, 32, 32, 32, 0, 1);
  k_cvt_x<<<dim3(32,16,8), 256, 0, stream>>>(C5, c5n, 1024, 16, 16, 16, 0, 1);

  // ================= BA phase =================
  // L3: scan -> SCR (NCHW), transpose -> CAT (4 NHWC group tensors), gemm.
  k_scan2<64, 6><<<2048, 256, 0, stream>>>(C3, scr, 8);
  k_tr<<<dim3(16,64,32), 256, 0, stream>>>(scr, catb, 256, 64, 2);
  {
    Epi ep = {ba3_b, nullptr,0,0,0, nullptr,0,0,0, nullptr,nullptr,0,0,0, c3ba,64,0,0, nullptr};
    k_gemm<5,1,1,true><<<dim3(256,2,1), 256, 0, stream>>>(
        catb, c3n, wsu + WR_BA3, nullptr, 256, 8, 15, 0, 12, 6, 1280, 1280, 256, 32768, ep);
  }
  // L4
  k_scan2<32, 5><<<4096, 256, 0, stream>>>(C4, scr, 9);
  k_tr<<<dim3(16,32,32), 256, 0, stream>>>(scr, catb, 512, 32, 1);
  {
    Epi ep = {ba4_b, nullptr,0,0,0, nullptr,0,0,0, nullptr,nullptr,0,0,0, c4ba,32,0,0, nullptr};
    k_gemm<5,1,1,true><<<dim3(64,4,1), 256, 0, stream>>>(
        catb, c4n, wsu + WR_BA4, nullptr, 512, 9, 13, 0, 10, 5, 2560, 2560, 512, 8192, ep);
  }
  // L5 (split-K 2)
  k_scan2<16, 4><<<8192, 256, 0, stream>>>(C5, scr, 10);
  k_tr<<<dim3(32,16,32), 256, 0, stream>>>(scr, catb, 1024, 16, 1);
  k_gemm<5,1,1,false><<<dim3(16,8,2), 256, 0, stream>>>(
      catb, c5n, wsu + WR_BA5, partba, 1024, 10, 11, 0, 8, 4, 5120, 2560, 1024, 2048, enone);
  {
    Epi ep = {ba5_b, nullptr,0,0,0, nullptr,0,0,0, nullptr,nullptr,0,0,0, c5ba,16,0,0, nullptr};
    k_red<<<2048, 256, 0, stream>>>(partba, 2, 1024, 11, 8, 4, ep);
  }

  // ---- CAT area now free: zero padded persistents, build c5p ----
  hipMemsetAsync(p3d, 0, (size_t)8921088 * 2, stream);
  hipMemsetAsync(p3pre, 0, (size_t)8921088 * 2, stream);
  hipMemsetAsync(p4pre, 0, (size_t)2367488 * 2, stream);
  hipMemsetAsync(p5pre, 0, (size_t)663552 * 2, stream);
  hipMemsetAsync(p6r, 0, (size_t)204800 * 2, stream);
  hipMemsetAsync(c5p, 0, (size_t)2654208 * 2, stream);
  k_cvt_x<<<dim3(32,16,8), 256, 0, stream>>>(C5, c5p, 1024, 16, 16, 18, 1, 1);

  // ================= dual (bottom-up) path =================
  {
    Epi ep = {p3_1d_b, nullptr,0,0,0, nullptr,0,0,0, nullptr,nullptr,0,0,0, p3d,66,1,0, nullptr};
    k_gemm<1,1,1,true><<<dim3(256,2,1), 256, 0, stream>>>(
        c3ba, nullptr, wsu + WR_P31D, nullptr, 256, 0, 64, 0, 12, 6, 256, 256, 256, 32768, ep);
  }
  k_gemm<9,3,2,false><<<dim3(64,2,2), 256, 0, stream>>>(
      p3d, nullptr, wsu + WR_C34, part, 256, 8, 66, 0, 10, 5, 2304, 1152, 256, 8192, enone);
  {
    Epi ep = {c34_b, nullptr,0,0,0, nullptr,0,0,0, nullptr,nullptr,0,0,0, p3d1,32,0,0, nullptr};
    k_red<<<2048, 256, 0, stream>>>(part, 2, 256, 13, 10, 5, ep);
  }
  k_gemm<4,2,2,false><<<dim3(16,2,8), 256, 0, stream>>>(
      p3d1, nullptr, wsu + WR_C35, part, 256, 8, 32, 0, 8, 4, 1024, 128, 256, 2048, enone);
  {
    Epi ep = {c35_b, nullptr,0,0,0, nullptr,0,0,0, nullptr,nullptr,0,0,0, p3d2,16,0,0, nullptr};
    k_red<<<2048, 256, 0, stream>>>(part, 8, 256, 11, 8, 4, ep);
  }
  k_gemm<1,1,1,false><<<dim3(64,2,2), 256, 0, stream>>>(
      c4ba, nullptr, wsu + WR_P41D, part, 512, 0, 32, 0, 10, 5, 512, 256, 256, 8192, enone);
  {
    Epi ep = {p4_1d_b, p3d1,32,0,0, nullptr,0,0,0, nullptr,nullptr,0,0,0, p4d,32,0,0, nullptr};
    k_red<<<2048, 256, 0, stream>>>(part, 2, 256, 13, 10, 5, ep);
  }
  k_gemm<4,2,2,false><<<dim3(16,2,8), 256, 0, stream>>>(
      p4d, nullptr, wsu + WR_C45, part, 256, 8, 32, 0, 8, 4, 1024, 128, 256, 2048, enone);
  {
    Epi ep = {c45_b, nullptr,0,0,0, nullptr,0,0,0, nullptr,nullptr,0,0,0, p4d1,16,0,0, nullptr};
    k_red<<<2048, 256, 0, stream>>>(part, 8, 256, 11, 8, 4, ep);
  }

  // ================= top-down path =================
  k_gemm<1,1,1,false><<<dim3(16,2,8), 256, 0, stream>>>(
      c5n, nullptr, wsu + WR_P51, part, 1024, 0, 16, 0, 8, 4, 1024, 128, 256, 2048, enone);
  {
    Epi ep = {p5_1_b, nullptr,0,0,0, nullptr,0,0,0, nullptr,nullptr,0,0,0, p5pre,18,1,0, nullptr};
    k_red<<<2048, 256, 0, stream>>>(part, 8, 256, 11, 8, 4, ep);
  }
  k_gemm<9,3,1,false><<<dim3(16,2,8), 256, 0, stream>>>(
      p5pre, nullptr, wsu + WR_P52, part, 256, 8, 18, 0, 8, 4, 2304, 288, 256, 2048, enone);
  {
    Epi ep = {p5_2_b, nullptr,0,0,0, nullptr,0,0,0, nullptr,nullptr,0,0,0, p5s,16,0,0, nullptr};
    k_red<<<2048, 256, 0, stream>>>(part, 8, 256, 11, 8, 4, ep);
  }
  k_gemm<1,1,1,false><<<dim3(64,2,2), 256, 0, stream>>>(
      c4n, nullptr, wsu + WR_P41, part, 512, 0, 32, 0, 10, 5, 512, 256, 256, 8192, enone);
  {
    Epi ep = {p4_1_b, p5pre,18,1,1, nullptr,0,0,0, nullptr,nullptr,0,0,0, p4pre,34,1,0, nullptr};
    k_red<<<2048, 256, 0, stream>>>(part, 2, 256, 13, 10, 5, ep);
  }
  k_gemm<9,3,1,false><<<dim3(64,2,2), 256, 0, stream>>>(
      p4pre, nullptr, wsu + WR_P42, part, 256, 8, 34, 0, 10, 5, 2304, 1152, 256, 8192, enone);
  {
    Epi ep = {p4_2_b, nullptr,0,0,0, nullptr,0,0,0, g4,p4d,32,0,1, nullptr,0,0,0, O4};
    k_red<<<2048, 256, 0, stream>>>(part, 2, 256, 13, 10, 5, ep);
  }
  {
    Epi ep = {p3_1_b, p4pre,34,1,1, p5pre,18,1,2, nullptr,nullptr,0,0,0, p3pre,66,1,0, nullptr};
    k_gemm<1,1,1,true><<<dim3(256,2,1), 256, 0, stream>>>(
        c3n, nullptr, wsu + WR_P31, nullptr, 256, 0, 64, 0, 12, 6, 256, 256, 256, 32768, ep);
  }
  {
    Epi ep = {p3_2_b, nullptr,0,0,0, nullptr,0,0,0, g3,p3d,66,1,1, nullptr,0,0,0, O3};
    k_gemm<9,3,1,true><<<dim3(256,2,1), 256, 0, stream>>>(
        p3pre, nullptr, wsu + WR_P32, nullptr, 256, 8, 66, 0, 12, 6, 2304, 2304, 256, 32768, ep);
  }
  k_gemm<1,1,1,false><<<dim3(16,2,8), 256, 0, stream>>>(
      c5ba, nullptr, wsu + WR_P51D, part, 1024, 0, 16, 0, 8, 4, 1024, 128, 256, 2048, enone);
  {
    Epi ep = {p5_1d_b, p4d1,16,0,0, p3d2,16,0,0, g5,p5s,16,0,2, nullptr,0,0,0, O5};
    k_red<<<2048, 256, 0, stream>>>(part, 8, 256, 11, 8, 4, ep);
  }

  // ================= P6 / P7 =================
  k_gemm<9,3,2,false><<<dim3(4,2,16), 256, 0, stream>>>(
      c5p, nullptr, wsu + WR_P6, part, 1024, 10, 18, 0, 6, 3, 9216, 576, 256, 512, enone);
  {
    Epi ep = {p6_b, nullptr,0,0,0, nullptr,0,0,0, nullptr,nullptr,0,0,0, p6r,10,1,1, P6o};
    k_red<<<512, 256, 0, stream>>>(part, 16, 256, 9, 6, 3, ep);
  }
  k_gemm<9,3,2,false><<<dim3(1,2,8), 256, 0, stream>>>(
      p6r, nullptr, wsu + WR_P7, part, 256, 8, 10, 0, 4, 2, 2304, 288, 256, 128, enone);
  {
    Epi ep = {p7_b, nullptr,0,0,0, nullptr,0,0,0, nullptr,nullptr,0,0,0, nullptr,0,0,0, P7o};
    k_red<<<128, 256, 0, stream>>>(part, 8, 256, 7, 4, 2, ep);
  }
}

// Round 5
// 873.423 us; speedup vs baseline: 3.0747x; 1.3215x over previous
//
#include <hip/hip_runtime.h>

typedef unsigned short u16;
typedef __attribute__((ext_vector_type(8))) short s8v;
typedef __attribute__((ext_vector_type(4))) float f4v;

__device__ __forceinline__ u16 f2bf(float f) {
  unsigned int x = __float_as_uint(f);
  return (u16)((x + 0x7fffu + ((x >> 16) & 1u)) >> 16);
}
__device__ __forceinline__ float bf2f(u16 u) {
  return __uint_as_float(((unsigned int)u) << 16);
}
__device__ __forceinline__ void gload16(const void* g, void* l) {
  __builtin_amdgcn_global_load_lds(
      (const __attribute__((address_space(1))) void*)g,
      (__attribute__((address_space(3))) void*)l, 16, 0, 0);
}

// ---------------------------------------------------------------------------
struct Epi {
  const float* bias;
  const u16* r1; int r1Hp, r1pad, r1sh;   // residual adds (C=256 NHWC)
  const u16* r2; int r2Hp, r2pad, r2sh;
  const float* gamma; const u16* other; int oHp, opad, gmode; // 1: g*o+(1-g)*v ; 2: g*v+(1-g)*o
  u16* outB; int oBHp, oBpad, oBrelu;     // bf16 NHWC out (C=M)
  float* outF;                             // fp32 NCHW out
};

__device__ __forceinline__ size_t nhwc_idx(int b, int h, int w, int Hp, int pad, int Cc, int m) {
  return (((size_t)(b * Hp + h + pad)) * Hp + (w + pad)) * Cc + m;
}

// scalar path (k_red)
__device__ __forceinline__ void epi_apply_store(float v, int m, int b, int oh, int ow,
                                                int p, int M, int l2ohow, float g, const Epi& ep) {
  if (ep.bias) v += ep.bias[m];
  if (ep.r1) v += bf2f(ep.r1[nhwc_idx(b, oh >> ep.r1sh, ow >> ep.r1sh, ep.r1Hp, ep.r1pad, 256, m)]);
  if (ep.r2) v += bf2f(ep.r2[nhwc_idx(b, oh >> ep.r2sh, ow >> ep.r2sh, ep.r2Hp, ep.r2pad, 256, m)]);
  if (ep.gmode) {
    float o = bf2f(ep.other[nhwc_idx(b, oh, ow, ep.oHp, ep.opad, 256, m)]);
    v = (ep.gmode == 1) ? (g * o + (1.f - g) * v) : (g * v + (1.f - g) * o);
  }
  if (ep.outF) ep.outF[(((size_t)(b * M + m)) << l2ohow) + p] = v;
  if (ep.outB) {
    float w = ep.oBrelu ? fmaxf(v, 0.f) : v;
    ep.outB[nhwc_idx(b, oh, ow, ep.oBHp, ep.oBpad, M, m)] = f2bf(w);
  }
}

// vector path (gemm FUSE): 4 consecutive m per call, packed ushort4 store
__device__ __forceinline__ void epi4(f4v a, int mbase, int b, int oh, int ow,
                                     int p, int M, int l2ohow, float g, const Epi& ep) {
  float v[4];
#pragma unroll
  for (int r = 0; r < 4; ++r) v[r] = a[r];
  if (ep.bias) {
    const float* bp = &ep.bias[mbase];
#pragma unroll
    for (int r = 0; r < 4; ++r) v[r] += bp[r];
  }
  if (ep.r1) {
    const u16* rp = &ep.r1[nhwc_idx(b, oh >> ep.r1sh, ow >> ep.r1sh, ep.r1Hp, ep.r1pad, 256, mbase)];
#pragma unroll
    for (int r = 0; r < 4; ++r) v[r] += bf2f(rp[r]);
  }
  if (ep.r2) {
    const u16* rp = &ep.r2[nhwc_idx(b, oh >> ep.r2sh, ow >> ep.r2sh, ep.r2Hp, ep.r2pad, 256, mbase)];
#pragma unroll
    for (int r = 0; r < 4; ++r) v[r] += bf2f(rp[r]);
  }
  if (ep.gmode) {
    const u16* op = &ep.other[nhwc_idx(b, oh, ow, ep.oHp, ep.opad, 256, mbase)];
#pragma unroll
    for (int r = 0; r < 4; ++r) {
      float o = bf2f(op[r]);
      v[r] = (ep.gmode == 1) ? (g * o + (1.f - g) * v[r]) : (g * v[r] + (1.f - g) * o);
    }
  }
  if (ep.outF) {
    float* fp = &ep.outF[(((size_t)(b * M + mbase)) << l2ohow) + p];
#pragma unroll
    for (int r = 0; r < 4; ++r) fp[(size_t)r << l2ohow] = v[r];
  }
  if (ep.outB) {
    u16* obp = &ep.outB[nhwc_idx(b, oh, ow, ep.oBHp, ep.oBpad, M, mbase)];
    ushort4 pk;
    if (ep.oBrelu) { pk.x = f2bf(fmaxf(v[0], 0.f)); pk.y = f2bf(fmaxf(v[1], 0.f));
                     pk.z = f2bf(fmaxf(v[2], 0.f)); pk.w = f2bf(fmaxf(v[3], 0.f)); }
    else { pk.x = f2bf(v[0]); pk.y = f2bf(v[1]); pk.z = f2bf(v[2]); pk.w = f2bf(v[3]); }
    *(ushort4*)obp = pk;
  }
}

// ---------------------------------------------------------------------------
// Weight convert/reorder, one block per (segment, m, ktile), 1 elem/thread.
// mode 0: fp32 OIHW -> bf16 [M][K'], k' = (kh*KW+kw)*Cin + c.
// mode 1 (BA): dst k' = g*C + c, g=0..3 = [prefH,sufH,prefW,sufW], g=4 = x.
// ---------------------------------------------------------------------------
struct WSeg { const float* src; u16* dst; int K, l2Cin, mode, ktiles, blk0; };
struct WTab { WSeg s[17]; };

__global__ __launch_bounds__(256) void k_cvt_w(WTab tab) {
  int bid = blockIdx.x;
  int si = 0;
#pragma unroll
  for (int i = 1; i < 17; ++i) si += (bid >= tab.s[i].blk0) ? 1 : 0;
  WSeg sg = tab.s[si];
  int rel = bid - sg.blk0;
  int m = rel / sg.ktiles;
  int kt = rel - m * sg.ktiles;
  int r = kt * 256 + threadIdx.x;
  if (r >= sg.K) return;
  int Cin = 1 << sg.l2Cin;
  int q = r >> sg.l2Cin, c = r & (Cin - 1);
  int sidx;
  if (sg.mode == 1) {
    int og = (q < 4) ? (q + 1) : 0;
    sidx = m * sg.K + og * Cin + c;
  } else {
    int KHW = sg.K >> sg.l2Cin;
    sidx = (m * Cin + c) * KHW + q;
  }
  sg.dst[(size_t)m * sg.K + r] = f2bf(sg.src[sidx]);
}

// ---------------------------------------------------------------------------
// NCHW fp32 -> NHWC bf16 (optional pad), LDS 32x32 transpose tiles.
// ---------------------------------------------------------------------------
__global__ __launch_bounds__(256) void k_cvt_x(const float* __restrict__ in, u16* __restrict__ out,
                                               int C, int H, int W, int Hp, int P, int tw) {
  __shared__ u16 tile[32][33];
  const int t = threadIdx.x;
  const int b = blockIdx.z, h = blockIdx.y;
  const int tc = blockIdx.x / tw, twi = blockIdx.x - tc * tw;
  const int c0 = tc * 32, w0 = twi * 32;
#pragma unroll
  for (int r = 0; r < 4; ++r) {
    int cl = (t >> 5) * 4 + r, wl = t & 31;
    if (w0 + wl < W) tile[cl][wl] = f2bf(in[(((size_t)b * C + c0 + cl) * H + h) * W + w0 + wl]);
  }
  __syncthreads();
#pragma unroll
  for (int r = 0; r < 4; ++r) {
    int wl = (t >> 5) * 4 + r, cl = t & 31;
    if (w0 + wl < W) out[(((size_t)(b * Hp + h + P)) * Hp + (w0 + wl + P)) * C + c0 + cl] = tile[cl][wl];
  }
}

// ---------------------------------------------------------------------------
// Cummax scans, coalesced NCHW bf16 out[g][b*C+c][S*S].
// ---------------------------------------------------------------------------
template<int S, int L2S>
__global__ __launch_bounds__(256) void k_scan2(const float* __restrict__ x,
                                               u16* __restrict__ out, int l2C) {
  __shared__ u16 pl[S][S + 1], rp[S][S + 1], rs[S][S + 1];
  const int pid = blockIdx.x;
  const size_t SS = (size_t)S * S;
  const size_t GS = ((size_t)8 << l2C) * SS;
  const float* xp = x + (size_t)pid * SS;
  u16* g0 = out + (size_t)pid * SS;
  u16* g1 = g0 + GS;
  u16* g2 = g1 + GS;
  u16* g3 = g2 + GS;
  const int t = threadIdx.x;
  for (int idx = t; idx < S * S; idx += 256)
    pl[idx >> L2S][idx & (S - 1)] = f2bf(xp[idx]);
  __syncthreads();
  if (t < S) {
    float m = -INFINITY;
    for (int h = 0; h < S; ++h) { m = fmaxf(m, bf2f(pl[h][t])); g0[h * S + t] = f2bf(m); }
  } else if (t < 2 * S) {
    int c = t - S;
    float m = -INFINITY;
    for (int h = S - 1; h >= 0; --h) { m = fmaxf(m, bf2f(pl[h][c])); g1[h * S + c] = f2bf(m); }
  } else if (t < 3 * S) {
    int h = t - 2 * S;
    float m = -INFINITY;
    for (int w = 0; w < S; ++w) { m = fmaxf(m, bf2f(pl[h][w])); rp[h][w] = f2bf(m); }
  } else if (t < 4 * S) {
    int h = t - 3 * S;
    float m = -INFINITY;
    for (int w = S - 1; w >= 0; --w) { m = fmaxf(m, bf2f(pl[h][w])); rs[h][w] = f2bf(m); }
  }
  __syncthreads();
  for (int idx = t; idx < S * S; idx += 256) {
    g2[idx] = rp[idx >> L2S][idx & (S - 1)];
    g3[idx] = rs[idx >> L2S][idx & (S - 1)];
  }
}

// ---------------------------------------------------------------------------
// bf16 NCHW -> NHWC transpose. src[z][C][S*S] -> dst[z][S*S][C], z = g*8+b.
// ---------------------------------------------------------------------------
__global__ __launch_bounds__(256) void k_tr(const u16* __restrict__ src, u16* __restrict__ dst,
                                            int C, int S, int tw) {
  __shared__ u16 tile[32][33];
  const int t = threadIdx.x;
  const int z = blockIdx.z, h = blockIdx.y;
  const int tc = blockIdx.x / tw, twi = blockIdx.x - tc * tw;
  const int c0 = tc * 32, w0 = twi * 32;
  const size_t SS = (size_t)S * S;
  const u16* sp = src + (size_t)z * C * SS;
  u16* dp = dst + (size_t)z * SS * C;
#pragma unroll
  for (int r = 0; r < 4; ++r) {
    int cl = (t >> 5) * 4 + r, wl = t & 31;
    if (w0 + wl < S) tile[cl][wl] = sp[(size_t)(c0 + cl) * SS + h * S + w0 + wl];
  }
  __syncthreads();
#pragma unroll
  for (int r = 0; r < 4; ++r) {
    int wl = (t >> 5) * 4 + r, cl = t & 31;
    if (w0 + wl < S) dp[((size_t)(h * S + w0 + wl)) * C + c0 + cl] = tile[cl][wl];
  }
}

// ---------------------------------------------------------------------------
// bf16 MFMA implicit-GEMM conv. 128x128 tile, BK=32, 4 waves (4x4 16x16x32).
// Staging: per operand per K-step, 8 gload16, each covering 16 rows x 64B
// (4 lanes/row, 8-ch chunk slot = (lane&3), source chunk = slot^(row&3) XOR
// swizzle; LDS linear [row][32ch]). Frag reads apply the same XOR.
// B pointers advance incrementally; tap/group recompute at block-uniform
// boundaries only. QDIV: 1 = 1x1, 4/9 = 2x2/3x3 taps, 5 = BA group mode.
// ---------------------------------------------------------------------------
template<int QDIV, int KW, int STR, bool FUSE>
__global__ __launch_bounds__(256)
void k_gemm(const u16* __restrict__ X, const u16* __restrict__ X2,
            const u16* __restrict__ Wt,
            float* __restrict__ part, int C, int l2C, int Hp, int ipad,
            int l2ohow, int l2ow, int K, int Ksp, int M, int N, Epi ep) {
  __shared__ u16 Al[4096];   // [128 rows][32 ch]
  __shared__ u16 Bl[4096];
  const int tid = threadIdx.x, lane = tid & 63, wid = tid >> 6;
  const int n0 = blockIdx.x * 128, m0 = blockIdx.y * 128;
  const int kb = blockIdx.z * Ksp;
  const int mw = (wid >> 1) * 64, nw = (wid & 1) * 64;

  const int srow = lane >> 2;                 // 0..15 row within 16-row group
  const int schunk = (lane & 3) ^ (srow & 3); // XOR-swizzled source chunk

  // A sources: weight rows m0 + wid*32 + j*16 + srow, contiguous in K.
  const u16* pa0 = Wt + (size_t)(m0 + wid * 32 + srow) * K + kb + schunk * 8;
  const u16* pa1 = pa0 + (size_t)16 * K;

  // B sources: pixel decode
  const u16* pb0 = nullptr; const u16* pb1 = nullptr;
  int rowB[2], ohsB[2], owsB[2];
  int q = 0, cnt = 0, khs = 0, kws = 0;
#pragma unroll
  for (int j = 0; j < 2; ++j) {
    int n = n0 + wid * 32 + j * 16 + srow;
    int b = n >> l2ohow, p = n & ((1 << l2ohow) - 1);
    int oh = p >> l2ow, ow = p & ((1 << l2ow) - 1);
    if (QDIV == 1) {
      const u16* gg = X + ((size_t)(b * Hp + oh + ipad) * Hp + (ow + ipad)) * C + kb + schunk * 8;
      if (j == 0) pb0 = gg; else pb1 = gg;
    } else if (QDIV == 5) {
      rowB[j] = n;
    } else {
      rowB[j] = b * Hp; ohsB[j] = oh * STR + ipad; owsB[j] = ow * STR + ipad;
    }
  }
  if (QDIV == 5) {
    q = kb >> l2C;
    int c0 = kb & (C - 1);
    cnt = (C - c0) >> 5;
    const u16* base = (q < 4) ? (X + (((size_t)q << Hp) << l2C)) : X2;
    pb0 = base + (((size_t)rowB[0]) << l2C) + c0 + schunk * 8;
    pb1 = base + (((size_t)rowB[1]) << l2C) + c0 + schunk * 8;
  } else if (QDIV != 1) {
    q = kb >> l2C;
    int c0 = kb & (C - 1);
    cnt = (C - c0) >> 5;
    if (QDIV == 4) { khs = q >> 1; kws = q & 1; } else { khs = q / 3; kws = q - khs * 3; }
    pb0 = X + ((size_t)(rowB[0] + ohsB[0] + khs) * Hp + (owsB[0] + kws)) * C + c0 + schunk * 8;
    pb1 = X + ((size_t)(rowB[1] + ohsB[1] + khs) * Hp + (owsB[1] + kws)) * C + c0 + schunk * 8;
  }

  f4v acc[4][4];
#pragma unroll
  for (int i = 0; i < 4; ++i)
#pragma unroll
    for (int j = 0; j < 4; ++j) acc[i][j] = (f4v){0.f, 0.f, 0.f, 0.f};

  u16* la = &Al[wid * 1024];
  u16* lb = &Bl[wid * 1024];
  const int fr = lane & 15, kc = lane >> 4;
  const int fxor = (kc ^ (lane & 3)) * 8;

  for (int ks = 0; ks < Ksp; ks += 32) {
    gload16(pa0, la); gload16(pa1, la + 512);
    gload16(pb0, lb); gload16(pb1, lb + 512);
    pa0 += 32; pa1 += 32;
    __syncthreads();
    s8v a[4], bv[4];
#pragma unroll
    for (int mf = 0; mf < 4; ++mf) a[mf] = *(const s8v*)&Al[(mw + mf * 16 + fr) * 32 + fxor];
#pragma unroll
    for (int nf = 0; nf < 4; ++nf) bv[nf] = *(const s8v*)&Bl[(nw + nf * 16 + fr) * 32 + fxor];
#pragma unroll
    for (int mf = 0; mf < 4; ++mf)
#pragma unroll
      for (int nf = 0; nf < 4; ++nf)
        acc[mf][nf] = __builtin_amdgcn_mfma_f32_16x16x32_bf16(a[mf], bv[nf], acc[mf][nf], 0, 0, 0);
    __syncthreads();
    // advance B
    if (QDIV == 1) { pb0 += 32; pb1 += 32; }
    else if (--cnt == 0) {
      ++q; cnt = C >> 5;
      if (QDIV == 5) {
        const u16* base = (q < 4) ? (X + (((size_t)q << Hp) << l2C)) : X2;
        pb0 = base + (((size_t)rowB[0]) << l2C) + schunk * 8;
        pb1 = base + (((size_t)rowB[1]) << l2C) + schunk * 8;
      } else {
        if (++kws == KW) { kws = 0; ++khs; }
        pb0 = X + ((size_t)(rowB[0] + ohsB[0] + khs) * Hp + (owsB[0] + kws)) * C + schunk * 8;
        pb1 = X + ((size_t)(rowB[1] + ohsB[1] + khs) * Hp + (owsB[1] + kws)) * C + schunk * 8;
      }
    } else { pb0 += 32; pb1 += 32; }
  }

  const int r4 = kc * 4;
  if (FUSE) {
    float g = ep.gmode ? *ep.gamma : 0.f;
#pragma unroll
    for (int nf = 0; nf < 4; ++nf) {
      int n = n0 + nw + nf * 16 + fr;
      int b = n >> l2ohow, p = n & ((1 << l2ohow) - 1);
      int oh = p >> l2ow, ow = p & ((1 << l2ow) - 1);
#pragma unroll
      for (int mf = 0; mf < 4; ++mf)
        epi4(acc[mf][nf], m0 + mw + mf * 16 + r4, b, oh, ow, p, M, l2ohow, g, ep);
    }
  } else {
#pragma unroll
    for (int mf = 0; mf < 4; ++mf)
#pragma unroll
      for (int r = 0; r < 4; ++r) {
        int m = m0 + mw + mf * 16 + r4 + r;
        float* pr = part + ((size_t)blockIdx.z * M + m) * N + n0 + nw + fr;
#pragma unroll
        for (int nf = 0; nf < 4; ++nf) pr[nf * 16] = acc[mf][nf][r];
      }
  }
}

// ---------------------------------------------------------------------------
// Split-K reduce + epilogue. part: [z][M][N] fp32, N = 1<<l2N.
// ---------------------------------------------------------------------------
__global__ __launch_bounds__(256) void k_red(const float* __restrict__ part, int z, int M,
                                             int l2N, int l2ohow, int l2ow, Epi ep) {
  size_t MN = ((size_t)M) << l2N;
  int N = 1 << l2N;
  float g = ep.gmode ? *ep.gamma : 0.f;
  for (size_t e = (size_t)blockIdx.x * 256 + threadIdx.x; e < MN; e += (size_t)gridDim.x * 256) {
    float v = 0.f;
    for (int s = 0; s < z; ++s) v += part[(size_t)s * MN + e];
    int m = (int)(e >> l2N), n = (int)(e & (N - 1));
    int b = n >> l2ohow, p = n & ((1 << l2ohow) - 1);
    int oh = p >> l2ow, ow = p & ((1 << l2ow) - 1);
    epi_apply_store(v, m, b, oh, ow, p, M, l2ohow, g, ep);
  }
}

// ---------------------------------------------------------------------------
// ws layout (u16 element offsets). Total 110,100,480 u16 = 220.2 MB.
// ---------------------------------------------------------------------------
static const size_t WR_BA3 = 0, WR_BA4 = 327680, WR_BA5 = 1638400,
  WR_P51 = 6881280, WR_P51D = 7143424, WR_P52 = 7405568, WR_P41 = 7995392,
  WR_P41D = 8126464, WR_P42 = 8257536, WR_P31 = 8847360, WR_P31D = 8912896,
  WR_P32 = 8978432, WR_P6 = 9568256, WR_P7 = 11927552, WR_C34 = 12517376,
  WR_C45 = 13107200, WR_C35 = 13369344;
static const size_t O_C3N = 13631488, O_C4N = 22020096, O_C5N = 26214400,
  O_C3BA = 28311552, O_C4BA = 36700160, O_C5BA = 40894464,
  O_CAT = 42991616, O_SCR = 76546048;
static const size_t O_P3D = O_CAT, O_P3PRE = O_CAT + 8921088,
  O_P4PRE = O_CAT + 17842176, O_P3D1 = O_CAT + 20209664,
  O_P4D = O_CAT + 22306816, O_P4D1 = O_CAT + 24403968,
  O_P3D2 = O_CAT + 24928256, O_P5PRE = O_CAT + 25452544,
  O_P5S = O_CAT + 26116096, O_P6R = O_CAT + 26640384, O_C5P = O_CAT + 26845184;

extern "C" void kernel_launch(void* const* d_in, const int* in_sizes, int n_in,
                              void* d_out, int out_size, void* d_ws, size_t ws_size,
                              hipStream_t stream) {
  (void)in_sizes; (void)n_in; (void)out_size; (void)ws_size;
  const float* C3 = (const float*)d_in[0];
  const float* C4 = (const float*)d_in[1];
  const float* C5 = (const float*)d_in[2];
  const float* ba3_w = (const float*)d_in[3];  const float* ba3_b = (const float*)d_in[4];
  const float* ba4_w = (const float*)d_in[5];  const float* ba4_b = (const float*)d_in[6];
  const float* ba5_w = (const float*)d_in[7];  const float* ba5_b = (const float*)d_in[8];
  const float* p5_1_w = (const float*)d_in[9];  const float* p5_1_b = (const float*)d_in[10];
  const float* p5_1d_w = (const float*)d_in[11]; const float* p5_1d_b = (const float*)d_in[12];
  const float* p5_2_w = (const float*)d_in[13]; const float* p5_2_b = (const float*)d_in[14];
  const float* p4_1_w = (const float*)d_in[15]; const float* p4_1_b = (const float*)d_in[16];
  const float* p4_1d_w = (const float*)d_in[17]; const float* p4_1d_b = (const float*)d_in[18];
  const float* p4_2_w = (const float*)d_in[19]; const float* p4_2_b = (const float*)d_in[20];
  const float* p3_1_w = (const float*)d_in[21]; const float* p3_1_b = (const float*)d_in[22];
  const float* p3_1d_w = (const float*)d_in[23]; const float* p3_1d_b = (const float*)d_in[24];
  const float* p3_2_w = (const float*)d_in[25]; const float* p3_2_b = (const float*)d_in[26];
  const float* p6_w = (const float*)d_in[27]; const float* p6_b = (const float*)d_in[28];
  const float* p7_w = (const float*)d_in[29]; const float* p7_b = (const float*)d_in[30];
  const float* c34_w = (const float*)d_in[31]; const float* c34_b = (const float*)d_in[32];
  const float* c45_w = (const float*)d_in[33]; const float* c45_b = (const float*)d_in[34];
  const float* c35_w = (const float*)d_in[35]; const float* c35_b = (const float*)d_in[36];
  const float* g3 = (const float*)d_in[37];
  const float* g4 = (const float*)d_in[38];
  const float* g5 = (const float*)d_in[39];

  float* out = (float*)d_out;
  float* O3 = out;
  float* O4 = out + 8388608;
  float* O5 = out + 10485760;
  float* P6o = out + 11010048;
  float* P7o = out + 11141120;

  u16* wsu = (u16*)d_ws;
  u16* c3n = wsu + O_C3N;  u16* c4n = wsu + O_C4N;  u16* c5n = wsu + O_C5N;
  u16* c3ba = wsu + O_C3BA; u16* c4ba = wsu + O_C4BA; u16* c5ba = wsu + O_C5BA;
  u16* catb = wsu + O_CAT;
  u16* scr = wsu + O_SCR;
  u16* p3d = wsu + O_P3D;  u16* p3d1 = wsu + O_P3D1; u16* p3d2 = wsu + O_P3D2;
  u16* p4d = wsu + O_P4D;  u16* p4d1 = wsu + O_P4D1;
  u16* p5pre = wsu + O_P5PRE; u16* p5s = wsu + O_P5S; u16* p4pre = wsu + O_P4PRE;
  u16* p3pre = wsu + O_P3PRE; u16* p6r = wsu + O_P6R; u16* c5p = wsu + O_C5P;
  float* part = (float*)scr;
  float* partba = (float*)scr;

  const Epi enone = {nullptr, nullptr,0,0,0, nullptr,0,0,0, nullptr,nullptr,0,0,0, nullptr,0,0,0, nullptr};

  // ---- weight conversion ----
  WTab tab;
  int ti = 0, blk = 0;
  auto add = [&](const float* s, size_t off, int M, int K, int l2Cin, int mode) {
    int kt = (K + 255) / 256;
    tab.s[ti].src = s; tab.s[ti].dst = wsu + off; tab.s[ti].K = K;
    tab.s[ti].l2Cin = l2Cin; tab.s[ti].mode = mode;
    tab.s[ti].ktiles = kt; tab.s[ti].blk0 = blk;
    blk += M * kt; ++ti;
  };
  add(ba3_w, WR_BA3, 256, 1280, 8, 1);
  add(ba4_w, WR_BA4, 512, 2560, 9, 1);
  add(ba5_w, WR_BA5, 1024, 5120, 10, 1);
  add(p5_1_w, WR_P51, 256, 1024, 10, 0);
  add(p5_1d_w, WR_P51D, 256, 1024, 10, 0);
  add(p5_2_w, WR_P52, 256, 2304, 8, 0);
  add(p4_1_w, WR_P41, 256, 512, 9, 0);
  add(p4_1d_w, WR_P41D, 256, 512, 9, 0);
  add(p4_2_w, WR_P42, 256, 2304, 8, 0);
  add(p3_1_w, WR_P31, 256, 256, 8, 0);
  add(p3_1d_w, WR_P31D, 256, 256, 8, 0);
  add(p3_2_w, WR_P32, 256, 2304, 8, 0);
  add(p6_w, WR_P6, 256, 9216, 10, 0);
  add(p7_w, WR_P7, 256, 2304, 8, 0);
  add(c34_w, WR_C34, 256, 2304, 8, 0);
  add(c45_w, WR_C45, 256, 1024, 8, 0);
  add(c35_w, WR_C35, 256, 1024, 8, 0);
  k_cvt_w<<<blk, 256, 0, stream>>>(tab);

  // ---- input NHWC conversions ----
  k_cvt_x<<<dim3(16,64,8), 256, 0, stream>>>(C3, c3n, 256, 64, 64, 64, 0, 2);
  k_cvt_x<<<dim3(16,32,8), 256, 0, stream>>>(C4, c4n, 512, 32, 32, 32, 0, 1);
  k_cvt_x<<<dim3(32,16,8), 256, 0, stream>>>(C5, c5n, 1024, 16, 16, 16, 0, 1);

  // ================= BA phase =================
  k_scan2<64, 6><<<2048, 256, 0, stream>>>(C3, scr, 8);
  k_tr<<<dim3(16,64,32), 256, 0, stream>>>(scr, catb, 256, 64, 2);
  {
    Epi ep = {ba3_b, nullptr,0,0,0, nullptr,0,0,0, nullptr,nullptr,0,0,0, c3ba,64,0,0, nullptr};
    k_gemm<5,1,1,true><<<dim3(256,2,1), 256, 0, stream>>>(
        catb, c3n, wsu + WR_BA3, nullptr, 256, 8, 15, 0, 12, 6, 1280, 1280, 256, 32768, ep);
  }
  k_scan2<32, 5><<<4096, 256, 0, stream>>>(C4, scr, 9);
  k_tr<<<dim3(16,32,32), 256, 0, stream>>>(scr, catb, 512, 32, 1);
  {
    Epi ep = {ba4_b, nullptr,0,0,0, nullptr,0,0,0, nullptr,nullptr,0,0,0, c4ba,32,0,0, nullptr};
    k_gemm<5,1,1,true><<<dim3(64,4,1), 256, 0, stream>>>(
        catb, c4n, wsu + WR_BA4, nullptr, 512, 9, 13, 0, 10, 5, 2560, 2560, 512, 8192, ep);
  }
  k_scan2<16, 4><<<8192, 256, 0, stream>>>(C5, scr, 10);
  k_tr<<<dim3(32,16,32), 256, 0, stream>>>(scr, catb, 1024, 16, 1);
  k_gemm<5,1,1,false><<<dim3(16,8,2), 256, 0, stream>>>(
      catb, c5n, wsu + WR_BA5, partba, 1024, 10, 11, 0, 8, 4, 5120, 2560, 1024, 2048, enone);
  {
    Epi ep = {ba5_b, nullptr,0,0,0, nullptr,0,0,0, nullptr,nullptr,0,0,0, c5ba,16,0,0, nullptr};
    k_red<<<2048, 256, 0, stream>>>(partba, 2, 1024, 11, 8, 4, ep);
  }

  // ---- CAT area free: zero padded persistents, build c5p ----
  hipMemsetAsync(p3d, 0, (size_t)8921088 * 2, stream);
  hipMemsetAsync(p3pre, 0, (size_t)8921088 * 2, stream);
  hipMemsetAsync(p4pre, 0, (size_t)2367488 * 2, stream);
  hipMemsetAsync(p5pre, 0, (size_t)663552 * 2, stream);
  hipMemsetAsync(p6r, 0, (size_t)204800 * 2, stream);
  hipMemsetAsync(c5p, 0, (size_t)2654208 * 2, stream);
  k_cvt_x<<<dim3(32,16,8), 256, 0, stream>>>(C5, c5p, 1024, 16, 16, 18, 1, 1);

  // ================= dual (bottom-up) path =================
  {
    Epi ep = {p3_1d_b, nullptr,0,0,0, nullptr,0,0,0, nullptr,nullptr,0,0,0, p3d,66,1,0, nullptr};
    k_gemm<1,1,1,true><<<dim3(256,2,1), 256, 0, stream>>>(
        c3ba, nullptr, wsu + WR_P31D, nullptr, 256, 0, 64, 0, 12, 6, 256, 256, 256, 32768, ep);
  }
  k_gemm<9,3,2,false><<<dim3(64,2,2), 256, 0, stream>>>(
      p3d, nullptr, wsu + WR_C34, part, 256, 8, 66, 0, 10, 5, 2304, 1152, 256, 8192, enone);
  {
    Epi ep = {c34_b, nullptr,0,0,0, nullptr,0,0,0, nullptr,nullptr,0,0,0, p3d1,32,0,0, nullptr};
    k_red<<<2048, 256, 0, stream>>>(part, 2, 256, 13, 10, 5, ep);
  }
  k_gemm<4,2,2,false><<<dim3(16,2,8), 256, 0, stream>>>(
      p3d1, nullptr, wsu + WR_C35, part, 256, 8, 32, 0, 8, 4, 1024, 128, 256, 2048, enone);
  {
    Epi ep = {c35_b, nullptr,0,0,0, nullptr,0,0,0, nullptr,nullptr,0,0,0, p3d2,16,0,0, nullptr};
    k_red<<<2048, 256, 0, stream>>>(part, 8, 256, 11, 8, 4, ep);
  }
  k_gemm<1,1,1,false><<<dim3(64,2,2), 256, 0, stream>>>(
      c4ba, nullptr, wsu + WR_P41D, part, 512, 0, 32, 0, 10, 5, 512, 256, 256, 8192, enone);
  {
    Epi ep = {p4_1d_b, p3d1,32,0,0, nullptr,0,0,0, nullptr,nullptr,0,0,0, p4d,32,0,0, nullptr};
    k_red<<<2048, 256, 0, stream>>>(part, 2, 256, 13, 10, 5, ep);
  }
  k_gemm<4,2,2,false><<<dim3(16,2,8), 256, 0, stream>>>(
      p4d, nullptr, wsu + WR_C45, part, 256, 8, 32, 0, 8, 4, 1024, 128, 256, 2048, enone);
  {
    Epi ep = {c45_b, nullptr,0,0,0, nullptr,0,0,0, nullptr,nullptr,0,0,0, p4d1,16,0,0, nullptr};
    k_red<<<2048, 256, 0, stream>>>(part, 8, 256, 11, 8, 4, ep);
  }

  // ================= top-down path =================
  k_gemm<1,1,1,false><<<dim3(16,2,8), 256, 0, stream>>>(
      c5n, nullptr, wsu + WR_P51, part, 1024, 0, 16, 0, 8, 4, 1024, 128, 256, 2048, enone);
  {
    Epi ep = {p5_1_b, nullptr,0,0,0, nullptr,0,0,0, nullptr,nullptr,0,0,0, p5pre,18,1,0, nullptr};
    k_red<<<2048, 256, 0, stream>>>(part, 8, 256, 11, 8, 4, ep);
  }
  k_gemm<9,3,1,false><<<dim3(16,2,8), 256, 0, stream>>>(
      p5pre, nullptr, wsu + WR_P52, part, 256, 8, 18, 0, 8, 4, 2304, 288, 256, 2048, enone);
  {
    Epi ep = {p5_2_b, nullptr,0,0,0, nullptr,0,0,0, nullptr,nullptr,0,0,0, p5s,16,0,0, nullptr};
    k_red<<<2048, 256, 0, stream>>>(part, 8, 256, 11, 8, 4, ep);
  }
  k_gemm<1,1,1,false><<<dim3(64,2,2), 256, 0, stream>>>(
      c4n, nullptr, wsu + WR_P41, part, 512, 0, 32, 0, 10, 5, 512, 256, 256, 8192, enone);
  {
    Epi ep = {p4_1_b, p5pre,18,1,1, nullptr,0,0,0, nullptr,nullptr,0,0,0, p4pre,34,1,0, nullptr};
    k_red<<<2048, 256, 0, stream>>>(part, 2, 256, 13, 10, 5, ep);
  }
  k_gemm<9,3,1,false><<<dim3(64,2,2), 256, 0, stream>>>(
      p4pre, nullptr, wsu + WR_P42, part, 256, 8, 34, 0, 10, 5, 2304, 1152, 256, 8192, enone);
  {
    Epi ep = {p4_2_b, nullptr,0,0,0, nullptr,0,0,0, g4,p4d,32,0,1, nullptr,0,0,0, O4};
    k_red<<<2048, 256, 0, stream>>>(part, 2, 256, 13, 10, 5, ep);
  }
  {
    Epi ep = {p3_1_b, p4pre,34,1,1, p5pre,18,1,2, nullptr,nullptr,0,0,0, p3pre,66,1,0, nullptr};
    k_gemm<1,1,1,true><<<dim3(256,2,1), 256, 0, stream>>>(
        c3n, nullptr, wsu + WR_P31, nullptr, 256, 0, 64, 0, 12, 6, 256, 256, 256, 32768, ep);
  }
  {
    Epi ep = {p3_2_b, nullptr,0,0,0, nullptr,0,0,0, g3,p3d,66,1,1, nullptr,0,0,0, O3};
    k_gemm<9,3,1,true><<<dim3(256,2,1), 256, 0, stream>>>(
        p3pre, nullptr, wsu + WR_P32, nullptr, 256, 8, 66, 0, 12, 6, 2304, 2304, 256, 32768, ep);
  }
  k_gemm<1,1,1,false><<<dim3(16,2,8), 256, 0, stream>>>(
      c5ba, nullptr, wsu + WR_P51D, part, 1024, 0, 16, 0, 8, 4, 1024, 128, 256, 2048, enone);
  {
    Epi ep = {p5_1d_b, p4d1,16,0,0, p3d2,16,0,0, g5,p5s,16,0,2, nullptr,0,0,0, O5};
    k_red<<<2048, 256, 0, stream>>>(part, 8, 256, 11, 8, 4, ep);
  }

  // ================= P6 / P7 =================
  k_gemm<9,3,2,false><<<dim3(4,2,16), 256, 0, stream>>>(
      c5p, nullptr, wsu + WR_P6, part, 1024, 10, 18, 0, 6, 3, 9216, 576, 256, 512, enone);
  {
    Epi ep = {p6_b, nullptr,0,0,0, nullptr,0,0,0, nullptr,nullptr,0,0,0, p6r,10,1,1, P6o};
    k_red<<<512, 256, 0, stream>>>(part, 16, 256, 9, 6, 3, ep);
  }
  k_gemm<9,3,2,false><<<dim3(1,2,8), 256, 0, stream>>>(
      p6r, nullptr, wsu + WR_P7, part, 256, 8, 10, 0, 4, 2, 2304, 288, 256, 128, enone);
  {
    Epi ep = {p7_b, nullptr,0,0,0, nullptr,0,0,0, nullptr,nullptr,0,0,0, nullptr,0,0,0, P7o};
    k_red<<<128, 256, 0, stream>>>(part, 8, 256, 7, 4, 2, ep);
  }
}

// Round 6
// 777.919 us; speedup vs baseline: 3.4522x; 1.1228x over previous
//
#include <hip/hip_runtime.h>

typedef unsigned short u16;
typedef __attribute__((ext_vector_type(8))) short s8v;
typedef __attribute__((ext_vector_type(4))) float f4v;

__device__ __forceinline__ u16 f2bf(float f) {
  unsigned int x = __float_as_uint(f);
  return (u16)((x + 0x7fffu + ((x >> 16) & 1u)) >> 16);
}
__device__ __forceinline__ float bf2f(u16 u) {
  return __uint_as_float(((unsigned int)u) << 16);
}
__device__ __forceinline__ void gload16(const void* g, void* l) {
  __builtin_amdgcn_global_load_lds(
      (const __attribute__((address_space(1))) void*)g,
      (__attribute__((address_space(3))) void*)l, 16, 0, 0);
}

// ---------------------------------------------------------------------------
struct Epi {
  const float* bias;
  const u16* r1; int r1Hp, r1pad, r1sh;   // residual adds (C=256 NHWC)
  const u16* r2; int r2Hp, r2pad, r2sh;
  const float* gamma; const u16* other; int oHp, opad, gmode; // 1: g*o+(1-g)*v ; 2: g*v+(1-g)*o
  u16* outB; int oBHp, oBpad, oBrelu;     // bf16 NHWC out (C=M)
  float* outF;                             // fp32 NCHW out
};

__device__ __forceinline__ size_t nhwc_idx(int b, int h, int w, int Hp, int pad, int Cc, int m) {
  return (((size_t)(b * Hp + h + pad)) * Hp + (w + pad)) * Cc + m;
}

// scalar path (k_red)
__device__ __forceinline__ void epi_apply_store(float v, int m, int b, int oh, int ow,
                                                int p, int M, int l2ohow, float g, const Epi& ep) {
  if (ep.bias) v += ep.bias[m];
  if (ep.r1) v += bf2f(ep.r1[nhwc_idx(b, oh >> ep.r1sh, ow >> ep.r1sh, ep.r1Hp, ep.r1pad, 256, m)]);
  if (ep.r2) v += bf2f(ep.r2[nhwc_idx(b, oh >> ep.r2sh, ow >> ep.r2sh, ep.r2Hp, ep.r2pad, 256, m)]);
  if (ep.gmode) {
    float o = bf2f(ep.other[nhwc_idx(b, oh, ow, ep.oHp, ep.opad, 256, m)]);
    v = (ep.gmode == 1) ? (g * o + (1.f - g) * v) : (g * v + (1.f - g) * o);
  }
  if (ep.outF) ep.outF[(((size_t)(b * M + m)) << l2ohow) + p] = v;
  if (ep.outB) {
    float w = ep.oBrelu ? fmaxf(v, 0.f) : v;
    ep.outB[nhwc_idx(b, oh, ow, ep.oBHp, ep.oBpad, M, m)] = f2bf(w);
  }
}

// vector path (gemm FUSE): 4 consecutive m per call, packed ushort4 store
__device__ __forceinline__ void epi4(f4v a, int mbase, int b, int oh, int ow,
                                     int p, int M, int l2ohow, float g, const Epi& ep) {
  float v[4];
#pragma unroll
  for (int r = 0; r < 4; ++r) v[r] = a[r];
  if (ep.bias) {
    const float* bp = &ep.bias[mbase];
#pragma unroll
    for (int r = 0; r < 4; ++r) v[r] += bp[r];
  }
  if (ep.r1) {
    const u16* rp = &ep.r1[nhwc_idx(b, oh >> ep.r1sh, ow >> ep.r1sh, ep.r1Hp, ep.r1pad, 256, mbase)];
#pragma unroll
    for (int r = 0; r < 4; ++r) v[r] += bf2f(rp[r]);
  }
  if (ep.r2) {
    const u16* rp = &ep.r2[nhwc_idx(b, oh >> ep.r2sh, ow >> ep.r2sh, ep.r2Hp, ep.r2pad, 256, mbase)];
#pragma unroll
    for (int r = 0; r < 4; ++r) v[r] += bf2f(rp[r]);
  }
  if (ep.gmode) {
    const u16* op = &ep.other[nhwc_idx(b, oh, ow, ep.oHp, ep.opad, 256, mbase)];
#pragma unroll
    for (int r = 0; r < 4; ++r) {
      float o = bf2f(op[r]);
      v[r] = (ep.gmode == 1) ? (g * o + (1.f - g) * v[r]) : (g * v[r] + (1.f - g) * o);
    }
  }
  if (ep.outF) {
    float* fp = &ep.outF[(((size_t)(b * M + mbase)) << l2ohow) + p];
#pragma unroll
    for (int r = 0; r < 4; ++r) fp[(size_t)r << l2ohow] = v[r];
  }
  if (ep.outB) {
    u16* obp = &ep.outB[nhwc_idx(b, oh, ow, ep.oBHp, ep.oBpad, M, mbase)];
    ushort4 pk;
    if (ep.oBrelu) { pk.x = f2bf(fmaxf(v[0], 0.f)); pk.y = f2bf(fmaxf(v[1], 0.f));
                     pk.z = f2bf(fmaxf(v[2], 0.f)); pk.w = f2bf(fmaxf(v[3], 0.f)); }
    else { pk.x = f2bf(v[0]); pk.y = f2bf(v[1]); pk.z = f2bf(v[2]); pk.w = f2bf(v[3]); }
    *(ushort4*)obp = pk;
  }
}

// ---------------------------------------------------------------------------
// Weight convert/reorder, one block per (segment, m, ktile), 1 elem/thread.
// ---------------------------------------------------------------------------
struct WSeg { const float* src; u16* dst; int K, l2Cin, mode, ktiles, blk0; };
struct WTab { WSeg s[17]; };

__global__ __launch_bounds__(256) void k_cvt_w(WTab tab) {
  int bid = blockIdx.x;
  int si = 0;
#pragma unroll
  for (int i = 1; i < 17; ++i) si += (bid >= tab.s[i].blk0) ? 1 : 0;
  WSeg sg = tab.s[si];
  int rel = bid - sg.blk0;
  int m = rel / sg.ktiles;
  int kt = rel - m * sg.ktiles;
  int r = kt * 256 + threadIdx.x;
  if (r >= sg.K) return;
  int Cin = 1 << sg.l2Cin;
  int q = r >> sg.l2Cin, c = r & (Cin - 1);
  int sidx;
  if (sg.mode == 1) {
    int og = (q < 4) ? (q + 1) : 0;
    sidx = m * sg.K + og * Cin + c;
  } else {
    int KHW = sg.K >> sg.l2Cin;
    sidx = (m * Cin + c) * KHW + q;
  }
  sg.dst[(size_t)m * sg.K + r] = f2bf(sg.src[sidx]);
}

// ---------------------------------------------------------------------------
// NCHW fp32 -> NHWC bf16 (optional pad), LDS 32x32 transpose tiles.
// ---------------------------------------------------------------------------
__global__ __launch_bounds__(256) void k_cvt_x(const float* __restrict__ in, u16* __restrict__ out,
                                               int C, int H, int W, int Hp, int P, int tw) {
  __shared__ u16 tile[32][33];
  const int t = threadIdx.x;
  const int b = blockIdx.z, h = blockIdx.y;
  const int tc = blockIdx.x / tw, twi = blockIdx.x - tc * tw;
  const int c0 = tc * 32, w0 = twi * 32;
#pragma unroll
  for (int r = 0; r < 4; ++r) {
    int cl = (t >> 5) * 4 + r, wl = t & 31;
    if (w0 + wl < W) tile[cl][wl] = f2bf(in[(((size_t)b * C + c0 + cl) * H + h) * W + w0 + wl]);
  }
  __syncthreads();
#pragma unroll
  for (int r = 0; r < 4; ++r) {
    int wl = (t >> 5) * 4 + r, cl = t & 31;
    if (w0 + wl < W) out[(((size_t)(b * Hp + h + P)) * Hp + (w0 + wl + P)) * C + c0 + cl] = tile[cl][wl];
  }
}

// ---------------------------------------------------------------------------
// Cummax scans, coalesced NCHW bf16 out[g][b*C+c][S*S].
// ---------------------------------------------------------------------------
template<int S, int L2S>
__global__ __launch_bounds__(256) void k_scan2(const float* __restrict__ x,
                                               u16* __restrict__ out, int l2C) {
  __shared__ u16 pl[S][S + 1], rp[S][S + 1], rs[S][S + 1];
  const int pid = blockIdx.x;
  const size_t SS = (size_t)S * S;
  const size_t GS = ((size_t)8 << l2C) * SS;
  const float* xp = x + (size_t)pid * SS;
  u16* g0 = out + (size_t)pid * SS;
  u16* g1 = g0 + GS;
  u16* g2 = g1 + GS;
  u16* g3 = g2 + GS;
  const int t = threadIdx.x;
  for (int idx = t; idx < S * S; idx += 256)
    pl[idx >> L2S][idx & (S - 1)] = f2bf(xp[idx]);
  __syncthreads();
  if (t < S) {
    float m = -INFINITY;
    for (int h = 0; h < S; ++h) { m = fmaxf(m, bf2f(pl[h][t])); g0[h * S + t] = f2bf(m); }
  } else if (t < 2 * S) {
    int c = t - S;
    float m = -INFINITY;
    for (int h = S - 1; h >= 0; --h) { m = fmaxf(m, bf2f(pl[h][c])); g1[h * S + c] = f2bf(m); }
  } else if (t < 3 * S) {
    int h = t - 2 * S;
    float m = -INFINITY;
    for (int w = 0; w < S; ++w) { m = fmaxf(m, bf2f(pl[h][w])); rp[h][w] = f2bf(m); }
  } else if (t < 4 * S) {
    int h = t - 3 * S;
    float m = -INFINITY;
    for (int w = S - 1; w >= 0; --w) { m = fmaxf(m, bf2f(pl[h][w])); rs[h][w] = f2bf(m); }
  }
  __syncthreads();
  for (int idx = t; idx < S * S; idx += 256) {
    g2[idx] = rp[idx >> L2S][idx & (S - 1)];
    g3[idx] = rs[idx >> L2S][idx & (S - 1)];
  }
}

// ---------------------------------------------------------------------------
// bf16 NCHW -> NHWC transpose. src[z][C][S*S] -> dst[z][S*S][C], z = g*8+b.
// ---------------------------------------------------------------------------
__global__ __launch_bounds__(256) void k_tr(const u16* __restrict__ src, u16* __restrict__ dst,
                                            int C, int S, int tw) {
  __shared__ u16 tile[32][33];
  const int t = threadIdx.x;
  const int z = blockIdx.z, h = blockIdx.y;
  const int tc = blockIdx.x / tw, twi = blockIdx.x - tc * tw;
  const int c0 = tc * 32, w0 = twi * 32;
  const size_t SS = (size_t)S * S;
  const u16* sp = src + (size_t)z * C * SS;
  u16* dp = dst + (size_t)z * SS * C;
#pragma unroll
  for (int r = 0; r < 4; ++r) {
    int cl = (t >> 5) * 4 + r, wl = t & 31;
    if (w0 + wl < S) tile[cl][wl] = sp[(size_t)(c0 + cl) * SS + h * S + w0 + wl];
  }
  __syncthreads();
#pragma unroll
  for (int r = 0; r < 4; ++r) {
    int wl = (t >> 5) * 4 + r, cl = t & 31;
    if (w0 + wl < S) dp[((size_t)(h * S + w0 + wl)) * C + c0 + cl] = tile[cl][wl];
  }
}

// ---------------------------------------------------------------------------
// bf16 MFMA implicit-GEMM conv. 128x128 tile, BK=32, 4 waves (4x4 16x16x32).
// 2-phase double-buffered pipeline: stage tile t+1 (4 gload16/wave) before
// computing tile t; raw s_barrier + counted s_waitcnt vmcnt(4) (never 0 in
// the main loop). LDS [2][128 rows][32 ch] per operand, XOR swizzle
// g(row)=(row>>1)&3 applied to source chunk and frag read (2-way only).
// ---------------------------------------------------------------------------
template<int QDIV, int KW, int STR, bool FUSE>
__global__ __launch_bounds__(256)
void k_gemm(const u16* __restrict__ X, const u16* __restrict__ X2,
            const u16* __restrict__ Wt,
            float* __restrict__ part, int C, int l2C, int Hp, int ipad,
            int l2ohow, int l2ow, int K, int Ksp, int M, int N, Epi ep) {
  __shared__ u16 Al[8192];   // [2][128 rows][32 ch]
  __shared__ u16 Bl[8192];
  const int tid = threadIdx.x, lane = tid & 63, wid = tid >> 6;
  const int n0 = blockIdx.x * 128, m0 = blockIdx.y * 128;
  const int kb = blockIdx.z * Ksp;
  const int mw = (wid >> 1) * 64, nw = (wid & 1) * 64;

  const int srow = lane >> 2;                        // row within 16-row group
  const int schunk = (lane & 3) ^ ((srow >> 1) & 3); // XOR-swizzled source chunk

  // A sources: weight rows m0 + wid*32 + j*16 + srow, contiguous in K.
  const u16* pa0 = Wt + (size_t)(m0 + wid * 32 + srow) * K + kb + schunk * 8;
  const u16* pa1 = pa0 + (size_t)16 * K;

  // B sources
  const u16* pb0 = nullptr; const u16* pb1 = nullptr;
  int rowB[2], ohsB[2], owsB[2];
  int q = 0, cnt = 0, khs = 0, kws = 0;
#pragma unroll
  for (int j = 0; j < 2; ++j) {
    int n = n0 + wid * 32 + j * 16 + srow;
    int b = n >> l2ohow, p = n & ((1 << l2ohow) - 1);
    int oh = p >> l2ow, ow = p & ((1 << l2ow) - 1);
    if (QDIV == 1) {
      const u16* gg = X + ((size_t)(b * Hp + oh + ipad) * Hp + (ow + ipad)) * C + kb + schunk * 8;
      if (j == 0) pb0 = gg; else pb1 = gg;
    } else if (QDIV == 5) {
      rowB[j] = n;
    } else {
      rowB[j] = b * Hp; ohsB[j] = oh * STR + ipad; owsB[j] = ow * STR + ipad;
    }
  }
  if (QDIV == 5) {
    q = kb >> l2C;
    int c0 = kb & (C - 1);
    cnt = (C - c0) >> 5;
    const u16* base = (q < 4) ? (X + (((size_t)q << Hp) << l2C)) : X2;
    pb0 = base + (((size_t)rowB[0]) << l2C) + c0 + schunk * 8;
    pb1 = base + (((size_t)rowB[1]) << l2C) + c0 + schunk * 8;
  } else if (QDIV != 1) {
    q = kb >> l2C;
    int c0 = kb & (C - 1);
    cnt = (C - c0) >> 5;
    if (QDIV == 4) { khs = q >> 1; kws = q & 1; } else { khs = q / 3; kws = q - khs * 3; }
    pb0 = X + ((size_t)(rowB[0] + ohsB[0] + khs) * Hp + (owsB[0] + kws)) * C + c0 + schunk * 8;
    pb1 = X + ((size_t)(rowB[1] + ohsB[1] + khs) * Hp + (owsB[1] + kws)) * C + c0 + schunk * 8;
  }

  f4v acc[4][4];
#pragma unroll
  for (int i = 0; i < 4; ++i)
#pragma unroll
    for (int j = 0; j < 4; ++j) acc[i][j] = (f4v){0.f, 0.f, 0.f, 0.f};

  const int wof = wid * 1024;
  const int fr = lane & 15, kc = lane >> 4;
  const int fxor = (kc ^ ((fr >> 1) & 3)) * 8;

  auto advB = [&]() {
    if (QDIV == 1) { pb0 += 32; pb1 += 32; }
    else if (--cnt == 0) {
      ++q; cnt = C >> 5;
      if (QDIV == 5) {
        const u16* base = (q < 4) ? (X + (((size_t)q << Hp) << l2C)) : X2;
        pb0 = base + (((size_t)rowB[0]) << l2C) + schunk * 8;
        pb1 = base + (((size_t)rowB[1]) << l2C) + schunk * 8;
      } else {
        if (++kws == KW) { kws = 0; ++khs; }
        pb0 = X + ((size_t)(rowB[0] + ohsB[0] + khs) * Hp + (owsB[0] + kws)) * C + schunk * 8;
        pb1 = X + ((size_t)(rowB[1] + ohsB[1] + khs) * Hp + (owsB[1] + kws)) * C + schunk * 8;
      }
    } else { pb0 += 32; pb1 += 32; }
  };
  auto stage = [&](int buf) {
    u16* la = Al + buf * 4096 + wof;
    u16* lb = Bl + buf * 4096 + wof;
    gload16(pa0, la); gload16(pa1, la + 512);
    gload16(pb0, lb); gload16(pb1, lb + 512);
    pa0 += 32; pa1 += 32;
    advB();
  };

  const int nt = Ksp >> 5;
  stage(0);
  for (int t = 0; t < nt; ++t) {
    const int cur = t & 1;
    if (t + 1 < nt) {
      stage(cur ^ 1);
      asm volatile("s_waitcnt vmcnt(4)" ::: "memory");
    } else {
      asm volatile("s_waitcnt vmcnt(0)" ::: "memory");
    }
    __builtin_amdgcn_s_barrier();
    asm volatile("" ::: "memory");
    const u16* ca = Al + cur * 4096;
    const u16* cb = Bl + cur * 4096;
    s8v a[4], bv[4];
#pragma unroll
    for (int mf = 0; mf < 4; ++mf) a[mf] = *(const s8v*)&ca[(mw + mf * 16 + fr) * 32 + fxor];
#pragma unroll
    for (int nf = 0; nf < 4; ++nf) bv[nf] = *(const s8v*)&cb[(nw + nf * 16 + fr) * 32 + fxor];
#pragma unroll
    for (int mf = 0; mf < 4; ++mf)
#pragma unroll
      for (int nf = 0; nf < 4; ++nf)
        acc[mf][nf] = __builtin_amdgcn_mfma_f32_16x16x32_bf16(a[mf], bv[nf], acc[mf][nf], 0, 0, 0);
    __builtin_amdgcn_s_barrier();
    asm volatile("" ::: "memory");
  }

  const int r4 = kc * 4;
  if (FUSE) {
    float g = ep.gmode ? *ep.gamma : 0.f;
#pragma unroll
    for (int nf = 0; nf < 4; ++nf) {
      int n = n0 + nw + nf * 16 + fr;
      int b = n >> l2ohow, p = n & ((1 << l2ohow) - 1);
      int oh = p >> l2ow, ow = p & ((1 << l2ow) - 1);
#pragma unroll
      for (int mf = 0; mf < 4; ++mf)
        epi4(acc[mf][nf], m0 + mw + mf * 16 + r4, b, oh, ow, p, M, l2ohow, g, ep);
    }
  } else {
#pragma unroll
    for (int mf = 0; mf < 4; ++mf)
#pragma unroll
      for (int r = 0; r < 4; ++r) {
        int m = m0 + mw + mf * 16 + r4 + r;
        float* pr = part + ((size_t)blockIdx.z * M + m) * N + n0 + nw + fr;
#pragma unroll
        for (int nf = 0; nf < 4; ++nf) pr[nf * 16] = acc[mf][nf][r];
      }
  }
}

// ---------------------------------------------------------------------------
// Split-K reduce + epilogue. part: [z][M][N] fp32, N = 1<<l2N.
// ---------------------------------------------------------------------------
__global__ __launch_bounds__(256) void k_red(const float* __restrict__ part, int z, int M,
                                             int l2N, int l2ohow, int l2ow, Epi ep) {
  size_t MN = ((size_t)M) << l2N;
  int N = 1 << l2N;
  float g = ep.gmode ? *ep.gamma : 0.f;
  for (size_t e = (size_t)blockIdx.x * 256 + threadIdx.x; e < MN; e += (size_t)gridDim.x * 256) {
    float v = 0.f;
    for (int s = 0; s < z; ++s) v += part[(size_t)s * MN + e];
    int m = (int)(e >> l2N), n = (int)(e & (N - 1));
    int b = n >> l2ohow, p = n & ((1 << l2ohow) - 1);
    int oh = p >> l2ow, ow = p & ((1 << l2ow) - 1);
    epi_apply_store(v, m, b, oh, ow, p, M, l2ohow, g, ep);
  }
}

// ---------------------------------------------------------------------------
// ws layout (u16 element offsets). Total 110,100,480 u16 = 220.2 MB.
// ---------------------------------------------------------------------------
static const size_t WR_BA3 = 0, WR_BA4 = 327680, WR_BA5 = 1638400,
  WR_P51 = 6881280, WR_P51D = 7143424, WR_P52 = 7405568, WR_P41 = 7995392,
  WR_P41D = 8126464, WR_P42 = 8257536, WR_P31 = 8847360, WR_P31D = 8912896,
  WR_P32 = 8978432, WR_P6 = 9568256, WR_P7 = 11927552, WR_C34 = 12517376,
  WR_C45 = 13107200, WR_C35 = 13369344;
static const size_t O_C3N = 13631488, O_C4N = 22020096, O_C5N = 26214400,
  O_C3BA = 28311552, O_C4BA = 36700160, O_C5BA = 40894464,
  O_CAT = 42991616, O_SCR = 76546048;
static const size_t O_P3D = O_CAT, O_P3PRE = O_CAT + 8921088,
  O_P4PRE = O_CAT + 17842176, O_P3D1 = O_CAT + 20209664,
  O_P4D = O_CAT + 22306816, O_P4D1 = O_CAT + 24403968,
  O_P3D2 = O_CAT + 24928256, O_P5PRE = O_CAT + 25452544,
  O_P5S = O_CAT + 26116096, O_P6R = O_CAT + 26640384, O_C5P = O_CAT + 26845184;

extern "C" void kernel_launch(void* const* d_in, const int* in_sizes, int n_in,
                              void* d_out, int out_size, void* d_ws, size_t ws_size,
                              hipStream_t stream) {
  (void)in_sizes; (void)n_in; (void)out_size; (void)ws_size;
  const float* C3 = (const float*)d_in[0];
  const float* C4 = (const float*)d_in[1];
  const float* C5 = (const float*)d_in[2];
  const float* ba3_w = (const float*)d_in[3];  const float* ba3_b = (const float*)d_in[4];
  const float* ba4_w = (const float*)d_in[5];  const float* ba4_b = (const float*)d_in[6];
  const float* ba5_w = (const float*)d_in[7];  const float* ba5_b = (const float*)d_in[8];
  const float* p5_1_w = (const float*)d_in[9];  const float* p5_1_b = (const float*)d_in[10];
  const float* p5_1d_w = (const float*)d_in[11]; const float* p5_1d_b = (const float*)d_in[12];
  const float* p5_2_w = (const float*)d_in[13]; const float* p5_2_b = (const float*)d_in[14];
  const float* p4_1_w = (const float*)d_in[15]; const float* p4_1_b = (const float*)d_in[16];
  const float* p4_1d_w = (const float*)d_in[17]; const float* p4_1d_b = (const float*)d_in[18];
  const float* p4_2_w = (const float*)d_in[19]; const float* p4_2_b = (const float*)d_in[20];
  const float* p3_1_w = (const float*)d_in[21]; const float* p3_1_b = (const float*)d_in[22];
  const float* p3_1d_w = (const float*)d_in[23]; const float* p3_1d_b = (const float*)d_in[24];
  const float* p3_2_w = (const float*)d_in[25]; const float* p3_2_b = (const float*)d_in[26];
  const float* p6_w = (const float*)d_in[27]; const float* p6_b = (const float*)d_in[28];
  const float* p7_w = (const float*)d_in[29]; const float* p7_b = (const float*)d_in[30];
  const float* c34_w = (const float*)d_in[31]; const float* c34_b = (const float*)d_in[32];
  const float* c45_w = (const float*)d_in[33]; const float* c45_b = (const float*)d_in[34];
  const float* c35_w = (const float*)d_in[35]; const float* c35_b = (const float*)d_in[36];
  const float* g3 = (const float*)d_in[37];
  const float* g4 = (const float*)d_in[38];
  const float* g5 = (const float*)d_in[39];

  float* out = (float*)d_out;
  float* O3 = out;
  float* O4 = out + 8388608;
  float* O5 = out + 10485760;
  float* P6o = out + 11010048;
  float* P7o = out + 11141120;

  u16* wsu = (u16*)d_ws;
  u16* c3n = wsu + O_C3N;  u16* c4n = wsu + O_C4N;  u16* c5n = wsu + O_C5N;
  u16* c3ba = wsu + O_C3BA; u16* c4ba = wsu + O_C4BA; u16* c5ba = wsu + O_C5BA;
  u16* catb = wsu + O_CAT;
  u16* scr = wsu + O_SCR;
  u16* p3d = wsu + O_P3D;  u16* p3d1 = wsu + O_P3D1; u16* p3d2 = wsu + O_P3D2;
  u16* p4d = wsu + O_P4D;  u16* p4d1 = wsu + O_P4D1;
  u16* p5pre = wsu + O_P5PRE; u16* p5s = wsu + O_P5S; u16* p4pre = wsu + O_P4PRE;
  u16* p3pre = wsu + O_P3PRE; u16* p6r = wsu + O_P6R; u16* c5p = wsu + O_C5P;
  float* part = (float*)scr;
  float* partba = (float*)scr;

  const Epi enone = {nullptr, nullptr,0,0,0, nullptr,0,0,0, nullptr,nullptr,0,0,0, nullptr,0,0,0, nullptr};

  // ---- weight conversion ----
  WTab tab;
  int ti = 0, blk = 0;
  auto add = [&](const float* s, size_t off, int M, int K, int l2Cin, int mode) {
    int kt = (K + 255) / 256;
    tab.s[ti].src = s; tab.s[ti].dst = wsu + off; tab.s[ti].K = K;
    tab.s[ti].l2Cin = l2Cin; tab.s[ti].mode = mode;
    tab.s[ti].ktiles = kt; tab.s[ti].blk0 = blk;
    blk += M * kt; ++ti;
  };
  add(ba3_w, WR_BA3, 256, 1280, 8, 1);
  add(ba4_w, WR_BA4, 512, 2560, 9, 1);
  add(ba5_w, WR_BA5, 1024, 5120, 10, 1);
  add(p5_1_w, WR_P51, 256, 1024, 10, 0);
  add(p5_1d_w, WR_P51D, 256, 1024, 10, 0);
  add(p5_2_w, WR_P52, 256, 2304, 8, 0);
  add(p4_1_w, WR_P41, 256, 512, 9, 0);
  add(p4_1d_w, WR_P41D, 256, 512, 9, 0);
  add(p4_2_w, WR_P42, 256, 2304, 8, 0);
  add(p3_1_w, WR_P31, 256, 256, 8, 0);
  add(p3_1d_w, WR_P31D, 256, 256, 8, 0);
  add(p3_2_w, WR_P32, 256, 2304, 8, 0);
  add(p6_w, WR_P6, 256, 9216, 10, 0);
  add(p7_w, WR_P7, 256, 2304, 8, 0);
  add(c34_w, WR_C34, 256, 2304, 8, 0);
  add(c45_w, WR_C45, 256, 1024, 8, 0);
  add(c35_w, WR_C35, 256, 1024, 8, 0);
  k_cvt_w<<<blk, 256, 0, stream>>>(tab);

  // ---- input NHWC conversions ----
  k_cvt_x<<<dim3(16,64,8), 256, 0, stream>>>(C3, c3n, 256, 64, 64, 64, 0, 2);
  k_cvt_x<<<dim3(16,32,8), 256, 0, stream>>>(C4, c4n, 512, 32, 32, 32, 0, 1);
  k_cvt_x<<<dim3(32,16,8), 256, 0, stream>>>(C5, c5n, 1024, 16, 16, 16, 0, 1);

  // ================= BA phase =================
  k_scan2<64, 6><<<2048, 256, 0, stream>>>(C3, scr, 8);
  k_tr<<<dim3(16,64,32), 256, 0, stream>>>(scr, catb, 256, 64, 2);
  {
    Epi ep = {ba3_b, nullptr,0,0,0, nullptr,0,0,0, nullptr,nullptr,0,0,0, c3ba,64,0,0, nullptr};
    k_gemm<5,1,1,true><<<dim3(256,2,1), 256, 0, stream>>>(
        catb, c3n, wsu + WR_BA3, nullptr, 256, 8, 15, 0, 12, 6, 1280, 1280, 256, 32768, ep);
  }
  k_scan2<32, 5><<<4096, 256, 0, stream>>>(C4, scr, 9);
  k_tr<<<dim3(16,32,32), 256, 0, stream>>>(scr, catb, 512, 32, 1);
  k_gemm<5,1,1,false><<<dim3(64,4,2), 256, 0, stream>>>(
      catb, c4n, wsu + WR_BA4, partba, 512, 9, 13, 0, 10, 5, 2560, 1280, 512, 8192, enone);
  {
    Epi ep = {ba4_b, nullptr,0,0,0, nullptr,0,0,0, nullptr,nullptr,0,0,0, c4ba,32,0,0, nullptr};
    k_red<<<2048, 256, 0, stream>>>(partba, 2, 512, 13, 10, 5, ep);
  }
  k_scan2<16, 4><<<8192, 256, 0, stream>>>(C5, scr, 10);
  k_tr<<<dim3(32,16,32), 256, 0, stream>>>(scr, catb, 1024, 16, 1);
  k_gemm<5,1,1,false><<<dim3(16,8,4), 256, 0, stream>>>(
      catb, c5n, wsu + WR_BA5, partba, 1024, 10, 11, 0, 8, 4, 5120, 1280, 1024, 2048, enone);
  {
    Epi ep = {ba5_b, nullptr,0,0,0, nullptr,0,0,0, nullptr,nullptr,0,0,0, c5ba,16,0,0, nullptr};
    k_red<<<2048, 256, 0, stream>>>(partba, 4, 1024, 11, 8, 4, ep);
  }

  // ---- CAT area free: zero padded persistents, build c5p ----
  hipMemsetAsync(p3d, 0, (size_t)8921088 * 2, stream);
  hipMemsetAsync(p3pre, 0, (size_t)8921088 * 2, stream);
  hipMemsetAsync(p4pre, 0, (size_t)2367488 * 2, stream);
  hipMemsetAsync(p5pre, 0, (size_t)663552 * 2, stream);
  hipMemsetAsync(p6r, 0, (size_t)204800 * 2, stream);
  hipMemsetAsync(c5p, 0, (size_t)2654208 * 2, stream);
  k_cvt_x<<<dim3(32,16,8), 256, 0, stream>>>(C5, c5p, 1024, 16, 16, 18, 1, 1);

  // ================= dual (bottom-up) path =================
  {
    Epi ep = {p3_1d_b, nullptr,0,0,0, nullptr,0,0,0, nullptr,nullptr,0,0,0, p3d,66,1,0, nullptr};
    k_gemm<1,1,1,true><<<dim3(256,2,1), 256, 0, stream>>>(
        c3ba, nullptr, wsu + WR_P31D, nullptr, 256, 0, 64, 0, 12, 6, 256, 256, 256, 32768, ep);
  }
  k_gemm<9,3,2,false><<<dim3(64,2,4), 256, 0, stream>>>(
      p3d, nullptr, wsu + WR_C34, part, 256, 8, 66, 0, 10, 5, 2304, 576, 256, 8192, enone);
  {
    Epi ep = {c34_b, nullptr,0,0,0, nullptr,0,0,0, nullptr,nullptr,0,0,0, p3d1,32,0,0, nullptr};
    k_red<<<2048, 256, 0, stream>>>(part, 4, 256, 13, 10, 5, ep);
  }
  k_gemm<4,2,2,false><<<dim3(16,2,8), 256, 0, stream>>>(
      p3d1, nullptr, wsu + WR_C35, part, 256, 8, 32, 0, 8, 4, 1024, 128, 256, 2048, enone);
  {
    Epi ep = {c35_b, nullptr,0,0,0, nullptr,0,0,0, nullptr,nullptr,0,0,0, p3d2,16,0,0, nullptr};
    k_red<<<2048, 256, 0, stream>>>(part, 8, 256, 11, 8, 4, ep);
  }
  k_gemm<1,1,1,false><<<dim3(64,2,4), 256, 0, stream>>>(
      c4ba, nullptr, wsu + WR_P41D, part, 512, 0, 32, 0, 10, 5, 512, 128, 256, 8192, enone);
  {
    Epi ep = {p4_1d_b, p3d1,32,0,0, nullptr,0,0,0, nullptr,nullptr,0,0,0, p4d,32,0,0, nullptr};
    k_red<<<2048, 256, 0, stream>>>(part, 4, 256, 13, 10, 5, ep);
  }
  k_gemm<4,2,2,false><<<dim3(16,2,8), 256, 0, stream>>>(
      p4d, nullptr, wsu + WR_C45, part, 256, 8, 32, 0, 8, 4, 1024, 128, 256, 2048, enone);
  {
    Epi ep = {c45_b, nullptr,0,0,0, nullptr,0,0,0, nullptr,nullptr,0,0,0, p4d1,16,0,0, nullptr};
    k_red<<<2048, 256, 0, stream>>>(part, 8, 256, 11, 8, 4, ep);
  }

  // ================= top-down path =================
  k_gemm<1,1,1,false><<<dim3(16,2,8), 256, 0, stream>>>(
      c5n, nullptr, wsu + WR_P51, part, 1024, 0, 16, 0, 8, 4, 1024, 128, 256, 2048, enone);
  {
    Epi ep = {p5_1_b, nullptr,0,0,0, nullptr,0,0,0, nullptr,nullptr,0,0,0, p5pre,18,1,0, nullptr};
    k_red<<<2048, 256, 0, stream>>>(part, 8, 256, 11, 8, 4, ep);
  }
  k_gemm<9,3,1,false><<<dim3(16,2,8), 256, 0, stream>>>(
      p5pre, nullptr, wsu + WR_P52, part, 256, 8, 18, 0, 8, 4, 2304, 288, 256, 2048, enone);
  {
    Epi ep = {p5_2_b, nullptr,0,0,0, nullptr,0,0,0, nullptr,nullptr,0,0,0, p5s,16,0,0, nullptr};
    k_red<<<2048, 256, 0, stream>>>(part, 8, 256, 11, 8, 4, ep);
  }
  k_gemm<1,1,1,false><<<dim3(64,2,4), 256, 0, stream>>>(
      c4n, nullptr, wsu + WR_P41, part, 512, 0, 32, 0, 10, 5, 512, 128, 256, 8192, enone);
  {
    Epi ep = {p4_1_b, p5pre,18,1,1, nullptr,0,0,0, nullptr,nullptr,0,0,0, p4pre,34,1,0, nullptr};
    k_red<<<2048, 256, 0, stream>>>(part, 4, 256, 13, 10, 5, ep);
  }
  k_gemm<9,3,1,false><<<dim3(64,2,4), 256, 0, stream>>>(
      p4pre, nullptr, wsu + WR_P42, part, 256, 8, 34, 0, 10, 5, 2304, 576, 256, 8192, enone);
  {
    Epi ep = {p4_2_b, nullptr,0,0,0, nullptr,0,0,0, g4,p4d,32,0,1, nullptr,0,0,0, O4};
    k_red<<<2048, 256, 0, stream>>>(part, 4, 256, 13, 10, 5, ep);
  }
  {
    Epi ep = {p3_1_b, p4pre,34,1,1, p5pre,18,1,2, nullptr,nullptr,0,0,0, p3pre,66,1,0, nullptr};
    k_gemm<1,1,1,true><<<dim3(256,2,1), 256, 0, stream>>>(
        c3n, nullptr, wsu + WR_P31, nullptr, 256, 0, 64, 0, 12, 6, 256, 256, 256, 32768, ep);
  }
  {
    Epi ep = {p3_2_b, nullptr,0,0,0, nullptr,0,0,0, g3,p3d,66,1,1, nullptr,0,0,0, O3};
    k_gemm<9,3,1,true><<<dim3(256,2,1), 256, 0, stream>>>(
        p3pre, nullptr, wsu + WR_P32, nullptr, 256, 8, 66, 0, 12, 6, 2304, 2304, 256, 32768, ep);
  }
  k_gemm<1,1,1,false><<<dim3(16,2,8), 256, 0, stream>>>(
      c5ba, nullptr, wsu + WR_P51D, part, 1024, 0, 16, 0, 8, 4, 1024, 128, 256, 2048, enone);
  {
    Epi ep = {p5_1d_b, p4d1,16,0,0, p3d2,16,0,0, g5,p5s,16,0,2, nullptr,0,0,0, O5};
    k_red<<<2048, 256, 0, stream>>>(part, 8, 256, 11, 8, 4, ep);
  }

  // ================= P6 / P7 =================
  k_gemm<9,3,2,false><<<dim3(4,2,32), 256, 0, stream>>>(
      c5p, nullptr, wsu + WR_P6, part, 1024, 10, 18, 0, 6, 3, 9216, 288, 256, 512, enone);
  {
    Epi ep = {p6_b, nullptr,0,0,0, nullptr,0,0,0, nullptr,nullptr,0,0,0, p6r,10,1,1, P6o};
    k_red<<<512, 256, 0, stream>>>(part, 32, 256, 9, 6, 3, ep);
  }
  k_gemm<9,3,2,false><<<dim3(1,2,8), 256, 0, stream>>>(
      p6r, nullptr, wsu + WR_P7, part, 256, 8, 10, 0, 4, 2, 2304, 288, 256, 128, enone);
  {
    Epi ep = {p7_b, nullptr,0,0,0, nullptr,0,0,0, nullptr,nullptr,0,0,0, nullptr,0,0,0, P7o};
    k_red<<<128, 256, 0, stream>>>(part, 8, 256, 7, 4, 2, ep);
  }
}

// Round 7
// 766.844 us; speedup vs baseline: 3.5020x; 1.0144x over previous
//
#include <hip/hip_runtime.h>

typedef unsigned short u16;
typedef __attribute__((ext_vector_type(8))) short s8v;
typedef __attribute__((ext_vector_type(4))) float f4v;

__device__ __forceinline__ u16 f2bf(float f) {
  unsigned int x = __float_as_uint(f);
  return (u16)((x + 0x7fffu + ((x >> 16) & 1u)) >> 16);
}
__device__ __forceinline__ float bf2f(u16 u) {
  return __uint_as_float(((unsigned int)u) << 16);
}
__device__ __forceinline__ void gload16(const void* g, void* l) {
  __builtin_amdgcn_global_load_lds(
      (const __attribute__((address_space(1))) void*)g,
      (__attribute__((address_space(3))) void*)l, 16, 0, 0);
}

// ---------------------------------------------------------------------------
struct Epi {
  const float* bias;
  const u16* r1; int r1Hp, r1pad, r1sh;   // residual adds (C=256 NHWC)
  const u16* r2; int r2Hp, r2pad, r2sh;
  const float* gamma; const u16* other; int oHp, opad, gmode; // 1: g*o+(1-g)*v ; 2: g*v+(1-g)*o
  u16* outB; int oBHp, oBpad, oBrelu;     // bf16 NHWC out (C=M)
  float* outF;                             // fp32 NCHW out
};

__device__ __forceinline__ size_t nhwc_idx(int b, int h, int w, int Hp, int pad, int Cc, int m) {
  return (((size_t)(b * Hp + h + pad)) * Hp + (w + pad)) * Cc + m;
}

// scalar path (k_red)
__device__ __forceinline__ void epi_apply_store(float v, int m, int b, int oh, int ow,
                                                int p, int M, int l2ohow, float g, const Epi& ep) {
  if (ep.bias) v += ep.bias[m];
  if (ep.r1) v += bf2f(ep.r1[nhwc_idx(b, oh >> ep.r1sh, ow >> ep.r1sh, ep.r1Hp, ep.r1pad, 256, m)]);
  if (ep.r2) v += bf2f(ep.r2[nhwc_idx(b, oh >> ep.r2sh, ow >> ep.r2sh, ep.r2Hp, ep.r2pad, 256, m)]);
  if (ep.gmode) {
    float o = bf2f(ep.other[nhwc_idx(b, oh, ow, ep.oHp, ep.opad, 256, m)]);
    v = (ep.gmode == 1) ? (g * o + (1.f - g) * v) : (g * v + (1.f - g) * o);
  }
  if (ep.outF) ep.outF[(((size_t)(b * M + m)) << l2ohow) + p] = v;
  if (ep.outB) {
    float w = ep.oBrelu ? fmaxf(v, 0.f) : v;
    ep.outB[nhwc_idx(b, oh, ow, ep.oBHp, ep.oBpad, M, m)] = f2bf(w);
  }
}

// vector path (gemm FUSE): 4 consecutive m per call, packed ushort4 store
__device__ __forceinline__ void epi4(f4v a, int mbase, int b, int oh, int ow,
                                     int p, int M, int l2ohow, float g, const Epi& ep) {
  float v[4];
#pragma unroll
  for (int r = 0; r < 4; ++r) v[r] = a[r];
  if (ep.bias) {
    const float* bp = &ep.bias[mbase];
#pragma unroll
    for (int r = 0; r < 4; ++r) v[r] += bp[r];
  }
  if (ep.r1) {
    const u16* rp = &ep.r1[nhwc_idx(b, oh >> ep.r1sh, ow >> ep.r1sh, ep.r1Hp, ep.r1pad, 256, mbase)];
#pragma unroll
    for (int r = 0; r < 4; ++r) v[r] += bf2f(rp[r]);
  }
  if (ep.r2) {
    const u16* rp = &ep.r2[nhwc_idx(b, oh >> ep.r2sh, ow >> ep.r2sh, ep.r2Hp, ep.r2pad, 256, mbase)];
#pragma unroll
    for (int r = 0; r < 4; ++r) v[r] += bf2f(rp[r]);
  }
  if (ep.gmode) {
    const u16* op = &ep.other[nhwc_idx(b, oh, ow, ep.oHp, ep.opad, 256, mbase)];
#pragma unroll
    for (int r = 0; r < 4; ++r) {
      float o = bf2f(op[r]);
      v[r] = (ep.gmode == 1) ? (g * o + (1.f - g) * v[r]) : (g * v[r] + (1.f - g) * o);
    }
  }
  if (ep.outF) {
    float* fp = &ep.outF[(((size_t)(b * M + mbase)) << l2ohow) + p];
#pragma unroll
    for (int r = 0; r < 4; ++r) fp[(size_t)r << l2ohow] = v[r];
  }
  if (ep.outB) {
    u16* obp = &ep.outB[nhwc_idx(b, oh, ow, ep.oBHp, ep.oBpad, M, mbase)];
    ushort4 pk;
    if (ep.oBrelu) { pk.x = f2bf(fmaxf(v[0], 0.f)); pk.y = f2bf(fmaxf(v[1], 0.f));
                     pk.z = f2bf(fmaxf(v[2], 0.f)); pk.w = f2bf(fmaxf(v[3], 0.f)); }
    else { pk.x = f2bf(v[0]); pk.y = f2bf(v[1]); pk.z = f2bf(v[2]); pk.w = f2bf(v[3]); }
    *(ushort4*)obp = pk;
  }
}

// ---------------------------------------------------------------------------
// Weight convert/reorder, one block per (segment, m, ktile), 1 elem/thread.
// ---------------------------------------------------------------------------
struct WSeg { const float* src; u16* dst; int K, l2Cin, mode, ktiles, blk0; };
struct WTab { WSeg s[17]; };

__global__ __launch_bounds__(256) void k_cvt_w(WTab tab) {
  int bid = blockIdx.x;
  int si = 0;
#pragma unroll
  for (int i = 1; i < 17; ++i) si += (bid >= tab.s[i].blk0) ? 1 : 0;
  WSeg sg = tab.s[si];
  int rel = bid - sg.blk0;
  int m = rel / sg.ktiles;
  int kt = rel - m * sg.ktiles;
  int r = kt * 256 + threadIdx.x;
  if (r >= sg.K) return;
  int Cin = 1 << sg.l2Cin;
  int q = r >> sg.l2Cin, c = r & (Cin - 1);
  int sidx;
  if (sg.mode == 1) {
    int og = (q < 4) ? (q + 1) : 0;
    sidx = m * sg.K + og * Cin + c;
  } else {
    int KHW = sg.K >> sg.l2Cin;
    sidx = (m * Cin + c) * KHW + q;
  }
  sg.dst[(size_t)m * sg.K + r] = f2bf(sg.src[sidx]);
}

// ---------------------------------------------------------------------------
// NCHW fp32 -> NHWC bf16 (optional pad), LDS 32x32 transpose tiles.
// ---------------------------------------------------------------------------
__global__ __launch_bounds__(256) void k_cvt_x(const float* __restrict__ in, u16* __restrict__ out,
                                               int C, int H, int W, int Hp, int P, int tw) {
  __shared__ u16 tile[32][33];
  const int t = threadIdx.x;
  const int b = blockIdx.z, h = blockIdx.y;
  const int tc = blockIdx.x / tw, twi = blockIdx.x - tc * tw;
  const int c0 = tc * 32, w0 = twi * 32;
#pragma unroll
  for (int r = 0; r < 4; ++r) {
    int cl = (t >> 5) * 4 + r, wl = t & 31;
    if (w0 + wl < W) tile[cl][wl] = f2bf(in[(((size_t)b * C + c0 + cl) * H + h) * W + w0 + wl]);
  }
  __syncthreads();
#pragma unroll
  for (int r = 0; r < 4; ++r) {
    int wl = (t >> 5) * 4 + r, cl = t & 31;
    if (w0 + wl < W) out[(((size_t)(b * Hp + h + P)) * Hp + (w0 + wl + P)) * C + c0 + cl] = tile[cl][wl];
  }
}

// ---------------------------------------------------------------------------
// Cummax scans, coalesced NCHW bf16 out[g][b*C+c][S*S].
// ---------------------------------------------------------------------------
template<int S, int L2S>
__global__ __launch_bounds__(256) void k_scan2(const float* __restrict__ x,
                                               u16* __restrict__ out, int l2C) {
  __shared__ u16 pl[S][S + 1], rp[S][S + 1], rs[S][S + 1];
  const int pid = blockIdx.x;
  const size_t SS = (size_t)S * S;
  const size_t GS = ((size_t)8 << l2C) * SS;
  const float* xp = x + (size_t)pid * SS;
  u16* g0 = out + (size_t)pid * SS;
  u16* g1 = g0 + GS;
  u16* g2 = g1 + GS;
  u16* g3 = g2 + GS;
  const int t = threadIdx.x;
  for (int idx = t; idx < S * S; idx += 256)
    pl[idx >> L2S][idx & (S - 1)] = f2bf(xp[idx]);
  __syncthreads();
  if (t < S) {
    float m = -INFINITY;
    for (int h = 0; h < S; ++h) { m = fmaxf(m, bf2f(pl[h][t])); g0[h * S + t] = f2bf(m); }
  } else if (t < 2 * S) {
    int c = t - S;
    float m = -INFINITY;
    for (int h = S - 1; h >= 0; --h) { m = fmaxf(m, bf2f(pl[h][c])); g1[h * S + c] = f2bf(m); }
  } else if (t < 3 * S) {
    int h = t - 2 * S;
    float m = -INFINITY;
    for (int w = 0; w < S; ++w) { m = fmaxf(m, bf2f(pl[h][w])); rp[h][w] = f2bf(m); }
  } else if (t < 4 * S) {
    int h = t - 3 * S;
    float m = -INFINITY;
    for (int w = S - 1; w >= 0; --w) { m = fmaxf(m, bf2f(pl[h][w])); rs[h][w] = f2bf(m); }
  }
  __syncthreads();
  for (int idx = t; idx < S * S; idx += 256) {
    g2[idx] = rp[idx >> L2S][idx & (S - 1)];
    g3[idx] = rs[idx >> L2S][idx & (S - 1)];
  }
}

// ---------------------------------------------------------------------------
// bf16 NCHW -> NHWC transpose. src[z][C][S*S] -> dst[z][S*S][C], z = g*8+b.
// ---------------------------------------------------------------------------
__global__ __launch_bounds__(256) void k_tr(const u16* __restrict__ src, u16* __restrict__ dst,
                                            int C, int S, int tw) {
  __shared__ u16 tile[32][33];
  const int t = threadIdx.x;
  const int z = blockIdx.z, h = blockIdx.y;
  const int tc = blockIdx.x / tw, twi = blockIdx.x - tc * tw;
  const int c0 = tc * 32, w0 = twi * 32;
  const size_t SS = (size_t)S * S;
  const u16* sp = src + (size_t)z * C * SS;
  u16* dp = dst + (size_t)z * SS * C;
#pragma unroll
  for (int r = 0; r < 4; ++r) {
    int cl = (t >> 5) * 4 + r, wl = t & 31;
    if (w0 + wl < S) tile[cl][wl] = sp[(size_t)(c0 + cl) * SS + h * S + w0 + wl];
  }
  __syncthreads();
#pragma unroll
  for (int r = 0; r < 4; ++r) {
    int wl = (t >> 5) * 4 + r, cl = t & 31;
    if (w0 + wl < S) dp[((size_t)(h * S + w0 + wl)) * C + c0 + cl] = tile[cl][wl];
  }
}

// ---------------------------------------------------------------------------
// bf16 MFMA implicit-GEMM conv. 128x128 tile, BK=32, 4 waves (4x4 16x16x32).
// 4-buffer, 2-ahead pipeline: stage tile t+2 while computing tile t; counted
// s_waitcnt vmcnt(8) in steady state (two 4-load stages in flight), one
// s_barrier per iteration (4 buffers make skew<=1 hazard-free).
// XOR swizzle g(row)=(row>>1)&3 on source chunk and frag read.
// ---------------------------------------------------------------------------
template<int QDIV, int KW, int STR, bool FUSE>
__global__ __launch_bounds__(256)
void k_gemm(const u16* __restrict__ X, const u16* __restrict__ X2,
            const u16* __restrict__ Wt,
            float* __restrict__ part, int C, int l2C, int Hp, int ipad,
            int l2ohow, int l2ow, int K, int Ksp, int M, int N, Epi ep) {
  __shared__ u16 Al[16384];   // [4][128 rows][32 ch]
  __shared__ u16 Bl[16384];
  const int tid = threadIdx.x, lane = tid & 63, wid = tid >> 6;
  const int n0 = blockIdx.x * 128, m0 = blockIdx.y * 128;
  const int kb = blockIdx.z * Ksp;
  const int mw = (wid >> 1) * 64, nw = (wid & 1) * 64;

  const int srow = lane >> 2;                        // row within 16-row group
  const int schunk = (lane & 3) ^ ((srow >> 1) & 3); // XOR-swizzled source chunk

  // A sources: weight rows m0 + wid*32 + j*16 + srow, contiguous in K.
  const u16* pa0 = Wt + (size_t)(m0 + wid * 32 + srow) * K + kb + schunk * 8;
  const u16* pa1 = pa0 + (size_t)16 * K;

  // B sources
  const u16* pb0 = nullptr; const u16* pb1 = nullptr;
  int rowB[2], ohsB[2], owsB[2];
  int q = 0, cnt = 0, khs = 0, kws = 0;
#pragma unroll
  for (int j = 0; j < 2; ++j) {
    int n = n0 + wid * 32 + j * 16 + srow;
    int b = n >> l2ohow, p = n & ((1 << l2ohow) - 1);
    int oh = p >> l2ow, ow = p & ((1 << l2ow) - 1);
    if (QDIV == 1) {
      const u16* gg = X + ((size_t)(b * Hp + oh + ipad) * Hp + (ow + ipad)) * C + kb + schunk * 8;
      if (j == 0) pb0 = gg; else pb1 = gg;
    } else if (QDIV == 5) {
      rowB[j] = n;
    } else {
      rowB[j] = b * Hp; ohsB[j] = oh * STR + ipad; owsB[j] = ow * STR + ipad;
    }
  }
  if (QDIV == 5) {
    q = kb >> l2C;
    int c0 = kb & (C - 1);
    cnt = (C - c0) >> 5;
    const u16* base = (q < 4) ? (X + (((size_t)q << Hp) << l2C)) : X2;
    pb0 = base + (((size_t)rowB[0]) << l2C) + c0 + schunk * 8;
    pb1 = base + (((size_t)rowB[1]) << l2C) + c0 + schunk * 8;
  } else if (QDIV != 1) {
    q = kb >> l2C;
    int c0 = kb & (C - 1);
    cnt = (C - c0) >> 5;
    if (QDIV == 4) { khs = q >> 1; kws = q & 1; } else { khs = q / 3; kws = q - khs * 3; }
    pb0 = X + ((size_t)(rowB[0] + ohsB[0] + khs) * Hp + (owsB[0] + kws)) * C + c0 + schunk * 8;
    pb1 = X + ((size_t)(rowB[1] + ohsB[1] + khs) * Hp + (owsB[1] + kws)) * C + c0 + schunk * 8;
  }

  f4v acc[4][4];
#pragma unroll
  for (int i = 0; i < 4; ++i)
#pragma unroll
    for (int j = 0; j < 4; ++j) acc[i][j] = (f4v){0.f, 0.f, 0.f, 0.f};

  const int wof = wid * 1024;
  const int fr = lane & 15, kc = lane >> 4;
  const int fxor = (kc ^ ((fr >> 1) & 3)) * 8;

  auto advB = [&]() {
    if (QDIV == 1) { pb0 += 32; pb1 += 32; }
    else if (--cnt == 0) {
      ++q; cnt = C >> 5;
      if (QDIV == 5) {
        const u16* base = (q < 4) ? (X + (((size_t)q << Hp) << l2C)) : X2;
        pb0 = base + (((size_t)rowB[0]) << l2C) + schunk * 8;
        pb1 = base + (((size_t)rowB[1]) << l2C) + schunk * 8;
      } else {
        if (++kws == KW) { kws = 0; ++khs; }
        pb0 = X + ((size_t)(rowB[0] + ohsB[0] + khs) * Hp + (owsB[0] + kws)) * C + schunk * 8;
        pb1 = X + ((size_t)(rowB[1] + ohsB[1] + khs) * Hp + (owsB[1] + kws)) * C + schunk * 8;
      }
    } else { pb0 += 32; pb1 += 32; }
  };
  auto stage = [&](int buf) {
    u16* la = Al + buf * 4096 + wof;
    u16* lb = Bl + buf * 4096 + wof;
    gload16(pa0, la); gload16(pa1, la + 512);
    gload16(pb0, lb); gload16(pb1, lb + 512);
    pa0 += 32; pa1 += 32;
    advB();
  };

  const int nt = Ksp >> 5;
  stage(0);
  if (nt > 1) stage(1);
  for (int t = 0; t < nt; ++t) {
    if (t + 2 < nt) {
      stage((t + 2) & 3);
      asm volatile("s_waitcnt vmcnt(8)" ::: "memory");
    } else if (t + 1 < nt) {
      asm volatile("s_waitcnt vmcnt(4)" ::: "memory");
    } else {
      asm volatile("s_waitcnt vmcnt(0)" ::: "memory");
    }
    __builtin_amdgcn_s_barrier();
    asm volatile("" ::: "memory");
    const u16* ca = Al + (t & 3) * 4096;
    const u16* cb = Bl + (t & 3) * 4096;
    s8v a[4], bv[4];
#pragma unroll
    for (int mf = 0; mf < 4; ++mf) a[mf] = *(const s8v*)&ca[(mw + mf * 16 + fr) * 32 + fxor];
#pragma unroll
    for (int nf = 0; nf < 4; ++nf) bv[nf] = *(const s8v*)&cb[(nw + nf * 16 + fr) * 32 + fxor];
#pragma unroll
    for (int mf = 0; mf < 4; ++mf)
#pragma unroll
      for (int nf = 0; nf < 4; ++nf)
        acc[mf][nf] = __builtin_amdgcn_mfma_f32_16x16x32_bf16(a[mf], bv[nf], acc[mf][nf], 0, 0, 0);
    asm volatile("" ::: "memory");
  }

  const int r4 = kc * 4;
  if (FUSE) {
    float g = ep.gmode ? *ep.gamma : 0.f;
#pragma unroll
    for (int nf = 0; nf < 4; ++nf) {
      int n = n0 + nw + nf * 16 + fr;
      int b = n >> l2ohow, p = n & ((1 << l2ohow) - 1);
      int oh = p >> l2ow, ow = p & ((1 << l2ow) - 1);
#pragma unroll
      for (int mf = 0; mf < 4; ++mf)
        epi4(acc[mf][nf], m0 + mw + mf * 16 + r4, b, oh, ow, p, M, l2ohow, g, ep);
    }
  } else {
#pragma unroll
    for (int mf = 0; mf < 4; ++mf)
#pragma unroll
      for (int r = 0; r < 4; ++r) {
        int m = m0 + mw + mf * 16 + r4 + r;
        float* pr = part + ((size_t)blockIdx.z * M + m) * N + n0 + nw + fr;
#pragma unroll
        for (int nf = 0; nf < 4; ++nf) pr[nf * 16] = acc[mf][nf][r];
      }
  }
}

// ---------------------------------------------------------------------------
// Split-K reduce + epilogue. part: [z][M][N] fp32, N = 1<<l2N.
// ---------------------------------------------------------------------------
__global__ __launch_bounds__(256) void k_red(const float* __restrict__ part, int z, int M,
                                             int l2N, int l2ohow, int l2ow, Epi ep) {
  size_t MN = ((size_t)M) << l2N;
  int N = 1 << l2N;
  float g = ep.gmode ? *ep.gamma : 0.f;
  for (size_t e = (size_t)blockIdx.x * 256 + threadIdx.x; e < MN; e += (size_t)gridDim.x * 256) {
    float v = 0.f;
    for (int s = 0; s < z; ++s) v += part[(size_t)s * MN + e];
    int m = (int)(e >> l2N), n = (int)(e & (N - 1));
    int b = n >> l2ohow, p = n & ((1 << l2ohow) - 1);
    int oh = p >> l2ow, ow = p & ((1 << l2ow) - 1);
    epi_apply_store(v, m, b, oh, ow, p, M, l2ohow, g, ep);
  }
}

// ---------------------------------------------------------------------------
// ws layout (u16 element offsets). Total 110,100,480 u16 = 220.2 MB.
// ---------------------------------------------------------------------------
static const size_t WR_BA3 = 0, WR_BA4 = 327680, WR_BA5 = 1638400,
  WR_P51 = 6881280, WR_P51D = 7143424, WR_P52 = 7405568, WR_P41 = 7995392,
  WR_P41D = 8126464, WR_P42 = 8257536, WR_P31 = 8847360, WR_P31D = 8912896,
  WR_P32 = 8978432, WR_P6 = 9568256, WR_P7 = 11927552, WR_C34 = 12517376,
  WR_C45 = 13107200, WR_C35 = 13369344;
static const size_t O_C3N = 13631488, O_C4N = 22020096, O_C5N = 26214400,
  O_C3BA = 28311552, O_C4BA = 36700160, O_C5BA = 40894464,
  O_CAT = 42991616, O_SCR = 76546048;
static const size_t O_P3D = O_CAT, O_P3PRE = O_CAT + 8921088,
  O_P4PRE = O_CAT + 17842176, O_P3D1 = O_CAT + 20209664,
  O_P4D = O_CAT + 22306816, O_P4D1 = O_CAT + 24403968,
  O_P3D2 = O_CAT + 24928256, O_P5PRE = O_CAT + 25452544,
  O_P5S = O_CAT + 26116096, O_P6R = O_CAT + 26640384, O_C5P = O_CAT + 26845184;

extern "C" void kernel_launch(void* const* d_in, const int* in_sizes, int n_in,
                              void* d_out, int out_size, void* d_ws, size_t ws_size,
                              hipStream_t stream) {
  (void)in_sizes; (void)n_in; (void)out_size; (void)ws_size;
  const float* C3 = (const float*)d_in[0];
  const float* C4 = (const float*)d_in[1];
  const float* C5 = (const float*)d_in[2];
  const float* ba3_w = (const float*)d_in[3];  const float* ba3_b = (const float*)d_in[4];
  const float* ba4_w = (const float*)d_in[5];  const float* ba4_b = (const float*)d_in[6];
  const float* ba5_w = (const float*)d_in[7];  const float* ba5_b = (const float*)d_in[8];
  const float* p5_1_w = (const float*)d_in[9];  const float* p5_1_b = (const float*)d_in[10];
  const float* p5_1d_w = (const float*)d_in[11]; const float* p5_1d_b = (const float*)d_in[12];
  const float* p5_2_w = (const float*)d_in[13]; const float* p5_2_b = (const float*)d_in[14];
  const float* p4_1_w = (const float*)d_in[15]; const float* p4_1_b = (const float*)d_in[16];
  const float* p4_1d_w = (const float*)d_in[17]; const float* p4_1d_b = (const float*)d_in[18];
  const float* p4_2_w = (const float*)d_in[19]; const float* p4_2_b = (const float*)d_in[20];
  const float* p3_1_w = (const float*)d_in[21]; const float* p3_1_b = (const float*)d_in[22];
  const float* p3_1d_w = (const float*)d_in[23]; const float* p3_1d_b = (const float*)d_in[24];
  const float* p3_2_w = (const float*)d_in[25]; const float* p3_2_b = (const float*)d_in[26];
  const float* p6_w = (const float*)d_in[27]; const float* p6_b = (const float*)d_in[28];
  const float* p7_w = (const float*)d_in[29]; const float* p7_b = (const float*)d_in[30];
  const float* c34_w = (const float*)d_in[31]; const float* c34_b = (const float*)d_in[32];
  const float* c45_w = (const float*)d_in[33]; const float* c45_b = (const float*)d_in[34];
  const float* c35_w = (const float*)d_in[35]; const float* c35_b = (const float*)d_in[36];
  const float* g3 = (const float*)d_in[37];
  const float* g4 = (const float*)d_in[38];
  const float* g5 = (const float*)d_in[39];

  float* out = (float*)d_out;
  float* O3 = out;
  float* O4 = out + 8388608;
  float* O5 = out + 10485760;
  float* P6o = out + 11010048;
  float* P7o = out + 11141120;

  u16* wsu = (u16*)d_ws;
  u16* c3n = wsu + O_C3N;  u16* c4n = wsu + O_C4N;  u16* c5n = wsu + O_C5N;
  u16* c3ba = wsu + O_C3BA; u16* c4ba = wsu + O_C4BA; u16* c5ba = wsu + O_C5BA;
  u16* catb = wsu + O_CAT;
  u16* scr = wsu + O_SCR;
  u16* p3d = wsu + O_P3D;  u16* p3d1 = wsu + O_P3D1; u16* p3d2 = wsu + O_P3D2;
  u16* p4d = wsu + O_P4D;  u16* p4d1 = wsu + O_P4D1;
  u16* p5pre = wsu + O_P5PRE; u16* p5s = wsu + O_P5S; u16* p4pre = wsu + O_P4PRE;
  u16* p3pre = wsu + O_P3PRE; u16* p6r = wsu + O_P6R; u16* c5p = wsu + O_C5P;
  float* part = (float*)scr;
  float* partba = (float*)scr;

  const Epi enone = {nullptr, nullptr,0,0,0, nullptr,0,0,0, nullptr,nullptr,0,0,0, nullptr,0,0,0, nullptr};

  // ---- weight conversion ----
  WTab tab;
  int ti = 0, blk = 0;
  auto add = [&](const float* s, size_t off, int M, int K, int l2Cin, int mode) {
    int kt = (K + 255) / 256;
    tab.s[ti].src = s; tab.s[ti].dst = wsu + off; tab.s[ti].K = K;
    tab.s[ti].l2Cin = l2Cin; tab.s[ti].mode = mode;
    tab.s[ti].ktiles = kt; tab.s[ti].blk0 = blk;
    blk += M * kt; ++ti;
  };
  add(ba3_w, WR_BA3, 256, 1280, 8, 1);
  add(ba4_w, WR_BA4, 512, 2560, 9, 1);
  add(ba5_w, WR_BA5, 1024, 5120, 10, 1);
  add(p5_1_w, WR_P51, 256, 1024, 10, 0);
  add(p5_1d_w, WR_P51D, 256, 1024, 10, 0);
  add(p5_2_w, WR_P52, 256, 2304, 8, 0);
  add(p4_1_w, WR_P41, 256, 512, 9, 0);
  add(p4_1d_w, WR_P41D, 256, 512, 9, 0);
  add(p4_2_w, WR_P42, 256, 2304, 8, 0);
  add(p3_1_w, WR_P31, 256, 256, 8, 0);
  add(p3_1d_w, WR_P31D, 256, 256, 8, 0);
  add(p3_2_w, WR_P32, 256, 2304, 8, 0);
  add(p6_w, WR_P6, 256, 9216, 10, 0);
  add(p7_w, WR_P7, 256, 2304, 8, 0);
  add(c34_w, WR_C34, 256, 2304, 8, 0);
  add(c45_w, WR_C45, 256, 1024, 8, 0);
  add(c35_w, WR_C35, 256, 1024, 8, 0);
  k_cvt_w<<<blk, 256, 0, stream>>>(tab);

  // ---- input NHWC conversions ----
  k_cvt_x<<<dim3(16,64,8), 256, 0, stream>>>(C3, c3n, 256, 64, 64, 64, 0, 2);
  k_cvt_x<<<dim3(16,32,8), 256, 0, stream>>>(C4, c4n, 512, 32, 32, 32, 0, 1);
  k_cvt_x<<<dim3(32,16,8), 256, 0, stream>>>(C5, c5n, 1024, 16, 16, 16, 0, 1);

  // ================= BA phase =================
  k_scan2<64, 6><<<2048, 256, 0, stream>>>(C3, scr, 8);
  k_tr<<<dim3(16,64,32), 256, 0, stream>>>(scr, catb, 256, 64, 2);
  {
    Epi ep = {ba3_b, nullptr,0,0,0, nullptr,0,0,0, nullptr,nullptr,0,0,0, c3ba,64,0,0, nullptr};
    k_gemm<5,1,1,true><<<dim3(256,2,1), 256, 0, stream>>>(
        catb, c3n, wsu + WR_BA3, nullptr, 256, 8, 15, 0, 12, 6, 1280, 1280, 256, 32768, ep);
  }
  k_scan2<32, 5><<<4096, 256, 0, stream>>>(C4, scr, 9);
  k_tr<<<dim3(16,32,32), 256, 0, stream>>>(scr, catb, 512, 32, 1);
  k_gemm<5,1,1,false><<<dim3(64,4,2), 256, 0, stream>>>(
      catb, c4n, wsu + WR_BA4, partba, 512, 9, 13, 0, 10, 5, 2560, 1280, 512, 8192, enone);
  {
    Epi ep = {ba4_b, nullptr,0,0,0, nullptr,0,0,0, nullptr,nullptr,0,0,0, c4ba,32,0,0, nullptr};
    k_red<<<2048, 256, 0, stream>>>(partba, 2, 512, 13, 10, 5, ep);
  }
  k_scan2<16, 4><<<8192, 256, 0, stream>>>(C5, scr, 10);
  k_tr<<<dim3(32,16,32), 256, 0, stream>>>(scr, catb, 1024, 16, 1);
  k_gemm<5,1,1,false><<<dim3(16,8,4), 256, 0, stream>>>(
      catb, c5n, wsu + WR_BA5, partba, 1024, 10, 11, 0, 8, 4, 5120, 1280, 1024, 2048, enone);
  {
    Epi ep = {ba5_b, nullptr,0,0,0, nullptr,0,0,0, nullptr,nullptr,0,0,0, c5ba,16,0,0, nullptr};
    k_red<<<2048, 256, 0, stream>>>(partba, 4, 1024, 11, 8, 4, ep);
  }

  // ---- CAT area free: zero padded persistents, build c5p ----
  hipMemsetAsync(p3d, 0, (size_t)8921088 * 2, stream);
  hipMemsetAsync(p3pre, 0, (size_t)8921088 * 2, stream);
  hipMemsetAsync(p4pre, 0, (size_t)2367488 * 2, stream);
  hipMemsetAsync(p5pre, 0, (size_t)663552 * 2, stream);
  hipMemsetAsync(p6r, 0, (size_t)204800 * 2, stream);
  hipMemsetAsync(c5p, 0, (size_t)2654208 * 2, stream);
  k_cvt_x<<<dim3(32,16,8), 256, 0, stream>>>(C5, c5p, 1024, 16, 16, 18, 1, 1);

  // ================= dual (bottom-up) path =================
  {
    Epi ep = {p3_1d_b, nullptr,0,0,0, nullptr,0,0,0, nullptr,nullptr,0,0,0, p3d,66,1,0, nullptr};
    k_gemm<1,1,1,true><<<dim3(256,2,1), 256, 0, stream>>>(
        c3ba, nullptr, wsu + WR_P31D, nullptr, 256, 0, 64, 0, 12, 6, 256, 256, 256, 32768, ep);
  }
  k_gemm<9,3,2,false><<<dim3(64,2,4), 256, 0, stream>>>(
      p3d, nullptr, wsu + WR_C34, part, 256, 8, 66, 0, 10, 5, 2304, 576, 256, 8192, enone);
  {
    Epi ep = {c34_b, nullptr,0,0,0, nullptr,0,0,0, nullptr,nullptr,0,0,0, p3d1,32,0,0, nullptr};
    k_red<<<2048, 256, 0, stream>>>(part, 4, 256, 13, 10, 5, ep);
  }
  k_gemm<4,2,2,false><<<dim3(16,2,8), 256, 0, stream>>>(
      p3d1, nullptr, wsu + WR_C35, part, 256, 8, 32, 0, 8, 4, 1024, 128, 256, 2048, enone);
  {
    Epi ep = {c35_b, nullptr,0,0,0, nullptr,0,0,0, nullptr,nullptr,0,0,0, p3d2,16,0,0, nullptr};
    k_red<<<2048, 256, 0, stream>>>(part, 8, 256, 11, 8, 4, ep);
  }
  k_gemm<1,1,1,false><<<dim3(64,2,4), 256, 0, stream>>>(
      c4ba, nullptr, wsu + WR_P41D, part, 512, 0, 32, 0, 10, 5, 512, 128, 256, 8192, enone);
  {
    Epi ep = {p4_1d_b, p3d1,32,0,0, nullptr,0,0,0, nullptr,nullptr,0,0,0, p4d,32,0,0, nullptr};
    k_red<<<2048, 256, 0, stream>>>(part, 4, 256, 13, 10, 5, ep);
  }
  k_gemm<4,2,2,false><<<dim3(16,2,8), 256, 0, stream>>>(
      p4d, nullptr, wsu + WR_C45, part, 256, 8, 32, 0, 8, 4, 1024, 128, 256, 2048, enone);
  {
    Epi ep = {c45_b, nullptr,0,0,0, nullptr,0,0,0, nullptr,nullptr,0,0,0, p4d1,16,0,0, nullptr};
    k_red<<<2048, 256, 0, stream>>>(part, 8, 256, 11, 8, 4, ep);
  }

  // ================= top-down path =================
  k_gemm<1,1,1,false><<<dim3(16,2,8), 256, 0, stream>>>(
      c5n, nullptr, wsu + WR_P51, part, 1024, 0, 16, 0, 8, 4, 1024, 128, 256, 2048, enone);
  {
    Epi ep = {p5_1_b, nullptr,0,0,0, nullptr,0,0,0, nullptr,nullptr,0,0,0, p5pre,18,1,0, nullptr};
    k_red<<<2048, 256, 0, stream>>>(part, 8, 256, 11, 8, 4, ep);
  }
  k_gemm<9,3,1,false><<<dim3(16,2,8), 256, 0, stream>>>(
      p5pre, nullptr, wsu + WR_P52, part, 256, 8, 18, 0, 8, 4, 2304, 288, 256, 2048, enone);
  {
    Epi ep = {p5_2_b, nullptr,0,0,0, nullptr,0,0,0, nullptr,nullptr,0,0,0, p5s,16,0,0, nullptr};
    k_red<<<2048, 256, 0, stream>>>(part, 8, 256, 11, 8, 4, ep);
  }
  k_gemm<1,1,1,false><<<dim3(64,2,4), 256, 0, stream>>>(
      c4n, nullptr, wsu + WR_P41, part, 512, 0, 32, 0, 10, 5, 512, 128, 256, 8192, enone);
  {
    Epi ep = {p4_1_b, p5pre,18,1,1, nullptr,0,0,0, nullptr,nullptr,0,0,0, p4pre,34,1,0, nullptr};
    k_red<<<2048, 256, 0, stream>>>(part, 4, 256, 13, 10, 5, ep);
  }
  k_gemm<9,3,1,false><<<dim3(64,2,4), 256, 0, stream>>>(
      p4pre, nullptr, wsu + WR_P42, part, 256, 8, 34, 0, 10, 5, 2304, 576, 256, 8192, enone);
  {
    Epi ep = {p4_2_b, nullptr,0,0,0, nullptr,0,0,0, g4,p4d,32,0,1, nullptr,0,0,0, O4};
    k_red<<<2048, 256, 0, stream>>>(part, 4, 256, 13, 10, 5, ep);
  }
  {
    Epi ep = {p3_1_b, p4pre,34,1,1, p5pre,18,1,2, nullptr,nullptr,0,0,0, p3pre,66,1,0, nullptr};
    k_gemm<1,1,1,true><<<dim3(256,2,1), 256, 0, stream>>>(
        c3n, nullptr, wsu + WR_P31, nullptr, 256, 0, 64, 0, 12, 6, 256, 256, 256, 32768, ep);
  }
  {
    Epi ep = {p3_2_b, nullptr,0,0,0, nullptr,0,0,0, g3,p3d,66,1,1, nullptr,0,0,0, O3};
    k_gemm<9,3,1,true><<<dim3(256,2,1), 256, 0, stream>>>(
        p3pre, nullptr, wsu + WR_P32, nullptr, 256, 8, 66, 0, 12, 6, 2304, 2304, 256, 32768, ep);
  }
  k_gemm<1,1,1,false><<<dim3(16,2,8), 256, 0, stream>>>(
      c5ba, nullptr, wsu + WR_P51D, part, 1024, 0, 16, 0, 8, 4, 1024, 128, 256, 2048, enone);
  {
    Epi ep = {p5_1d_b, p4d1,16,0,0, p3d2,16,0,0, g5,p5s,16,0,2, nullptr,0,0,0, O5};
    k_red<<<2048, 256, 0, stream>>>(part, 8, 256, 11, 8, 4, ep);
  }

  // ================= P6 / P7 =================
  k_gemm<9,3,2,false><<<dim3(4,2,32), 256, 0, stream>>>(
      c5p, nullptr, wsu + WR_P6, part, 1024, 10, 18, 0, 6, 3, 9216, 288, 256, 512, enone);
  {
    Epi ep = {p6_b, nullptr,0,0,0, nullptr,0,0,0, nullptr,nullptr,0,0,0, p6r,10,1,1, P6o};
    k_red<<<512, 256, 0, stream>>>(part, 32, 256, 9, 6, 3, ep);
  }
  k_gemm<9,3,2,false><<<dim3(1,2,8), 256, 0, stream>>>(
      p6r, nullptr, wsu + WR_P7, part, 256, 8, 10, 0, 4, 2, 2304, 288, 256, 128, enone);
  {
    Epi ep = {p7_b, nullptr,0,0,0, nullptr,0,0,0, nullptr,nullptr,0,0,0, nullptr,0,0,0, P7o};
    k_red<<<128, 256, 0, stream>>>(part, 8, 256, 7, 4, 2, ep);
  }
}